// Round 3
// baseline (846.399 us; speedup 1.0000x reference)
//
#include <hip/hip_runtime.h>
#include <hip/hip_bf16.h>

// Sizes (derived at launch, expected values):
// B=256, N=10000, E=160000, H1=1024, H2=128
// NOTE: harness passes integer inputs as int32 (edge_index -> const int*).
// NOTE: no hipMemsetAsync inside kernel_launch — zeroing done by kernels so
// graph replay provably re-executes it (memset nodes were the prime suspect
// for the round-2 post-timing divergence).

__global__ void zero4_kernel(float4* __restrict__ p, int n4) {
    int i = blockIdx.x * blockDim.x + threadIdx.x;
    if (i < n4) p[i] = make_float4(0.f, 0.f, 0.f, 0.f);
}

__global__ void deg_kernel(const int* __restrict__ dst, float* __restrict__ deg, int E) {
    int i = blockIdx.x * blockDim.x + threadIdx.x;
    if (i < E) atomicAdd(&deg[dst[i]], 1.0f);
}

__global__ void dinv_kernel(const float* __restrict__ deg, float* __restrict__ dinv, int N) {
    int n = blockIdx.x * blockDim.x + threadIdx.x;
    if (n < N) dinv[n] = rsqrtf(deg[n] + 1.0f);  // +1 = self-loop
}

// data [B][N] -> xwT [N][B], scaled by gcn_w
__global__ void transpose_scale(const float* __restrict__ data, const float* __restrict__ gw,
                                float* __restrict__ xwT, int N, int B) {
    __shared__ float tile[32][33];
    float w = gw[0];
    int n0 = blockIdx.x * 32, b0 = blockIdx.y * 32;
#pragma unroll
    for (int i = 0; i < 4; ++i) {
        int b = b0 + threadIdx.y + i * 8;
        int n = n0 + threadIdx.x;
        float v = (n < N) ? data[(size_t)b * N + n] : 0.f;
        tile[threadIdx.y + i * 8][threadIdx.x] = v * w;
    }
    __syncthreads();
#pragma unroll
    for (int i = 0; i < 4; ++i) {
        int n = n0 + threadIdx.y + i * 8;
        int b = b0 + threadIdx.x;
        if (n < N) xwT[(size_t)n * B + b] = tile[threadIdx.x][threadIdx.y + i * 8];
    }
}

// one wave per edge: aggT[dst][:] += xwT[src][:] * dinv[src]*dinv[dst]
__global__ void scatter_kernel(const int* __restrict__ ei, const float* __restrict__ dinv,
                               const float* __restrict__ xwT, float* __restrict__ aggT,
                               int E, int B) {
    int e = blockIdx.x * 4 + (threadIdx.x >> 6);
    if (e >= E) return;
    int lane = threadIdx.x & 63;
    int s = ei[e];
    int d = ei[E + e];
    float nrm = dinv[s] * dinv[d];
    const float4* src4 = (const float4*)(xwT + (size_t)s * B);
    float* dp = aggT + (size_t)d * B;
    float4 v = src4[lane];
    atomicAdd(&dp[lane * 4 + 0], v.x * nrm);
    atomicAdd(&dp[lane * 4 + 1], v.y * nrm);
    atomicAdd(&dp[lane * 4 + 2], v.z * nrm);
    atomicAdd(&dp[lane * 4 + 3], v.w * nrm);
}

// split-K fp32 GEMM: h_raw[m][n] += sum_k g[m][k] * W1[k][n]
// g[m][k] = relu(aggT[k][m] + xwT[k][m]*dinv[k]^2 + gcn_b)  (fused, A^T layout = native)
// BM=BN=64, KT=32, 20 K-steps per z-chunk (640), grid.z covers K
__global__ void gemm1_kernel(const float* __restrict__ aggT, const float* __restrict__ xwT,
                             const float* __restrict__ dinv, const float* __restrict__ W1,
                             const float* __restrict__ gcn_b, float* __restrict__ hraw,
                             int K, int B, int H1) {
    __shared__ float As[32][64];
    __shared__ float Bs[32][64];
    const int n0 = blockIdx.x * 64;
    const int m0 = blockIdx.y * 64;
    const int k0base = blockIdx.z * 640;
    const float gb = gcn_b[0];
    const int t = threadIdx.x;
    const int tx = t & 15, ty = t >> 4;
    float acc[4][4] = {};

    for (int ks = 0; ks < 20; ++ks) {
        int k0 = k0base + ks * 32;
#pragma unroll
        for (int i = 0; i < 8; ++i) {
            int idx = t + i * 256;
            int kk = idx >> 6, cc = idx & 63;
            int k = k0 + kk;
            float av = 0.f, bv = 0.f;
            if (k < K) {
                size_t off = (size_t)k * B + (m0 + cc);
                float di = dinv[k];
                av = fmaxf(aggT[off] + xwT[off] * di * di + gb, 0.f);
                bv = W1[(size_t)k * H1 + (n0 + cc)];
            }
            As[kk][cc] = av;
            Bs[kk][cc] = bv;
        }
        __syncthreads();
#pragma unroll 8
        for (int kk = 0; kk < 32; ++kk) {
            float a0 = As[kk][ty * 4 + 0], a1 = As[kk][ty * 4 + 1];
            float a2 = As[kk][ty * 4 + 2], a3 = As[kk][ty * 4 + 3];
            float b0 = Bs[kk][tx * 4 + 0], b1 = Bs[kk][tx * 4 + 1];
            float b2 = Bs[kk][tx * 4 + 2], b3 = Bs[kk][tx * 4 + 3];
            acc[0][0] = fmaf(a0, b0, acc[0][0]); acc[0][1] = fmaf(a0, b1, acc[0][1]);
            acc[0][2] = fmaf(a0, b2, acc[0][2]); acc[0][3] = fmaf(a0, b3, acc[0][3]);
            acc[1][0] = fmaf(a1, b0, acc[1][0]); acc[1][1] = fmaf(a1, b1, acc[1][1]);
            acc[1][2] = fmaf(a1, b2, acc[1][2]); acc[1][3] = fmaf(a1, b3, acc[1][3]);
            acc[2][0] = fmaf(a2, b0, acc[2][0]); acc[2][1] = fmaf(a2, b1, acc[2][1]);
            acc[2][2] = fmaf(a2, b2, acc[2][2]); acc[2][3] = fmaf(a2, b3, acc[2][3]);
            acc[3][0] = fmaf(a3, b0, acc[3][0]); acc[3][1] = fmaf(a3, b1, acc[3][1]);
            acc[3][2] = fmaf(a3, b2, acc[3][2]); acc[3][3] = fmaf(a3, b3, acc[3][3]);
        }
        __syncthreads();
    }
#pragma unroll
    for (int i = 0; i < 4; ++i) {
        int m = m0 + ty * 4 + i;
#pragma unroll
        for (int j = 0; j < 4; ++j) {
            atomicAdd(&hraw[(size_t)m * H1 + n0 + tx * 4 + j], acc[i][j]);
        }
    }
}

__global__ void bias_relu_kernel(float* __restrict__ h, const float* __restrict__ b1,
                                 int total, int H1) {
    int i = blockIdx.x * blockDim.x + threadIdx.x;
    if (i < total) h[i] = fmaxf(h[i] + b1[i & (H1 - 1)], 0.f);
}

// out[b][j] = relu(sum_k h[b][k]*W2[k][j] + b2[j]); block=256 (2 k-halves), grid=B
__global__ void gemm2_kernel(const float* __restrict__ h, const float* __restrict__ W2,
                             const float* __restrict__ b2, float* __restrict__ out,
                             int H1, int H2) {
    __shared__ float partial[256];
    int b = blockIdx.x;
    int t = threadIdx.x;
    int j = t & (H2 - 1);
    int half = t >> 7;
    const float* hrow = h + (size_t)b * H1;
    float sum = 0.f;
    int k0 = half * (H1 / 2), k1 = k0 + (H1 / 2);
    for (int k = k0; k < k1; ++k)
        sum = fmaf(hrow[k], W2[(size_t)k * H2 + j], sum);
    partial[t] = sum;
    __syncthreads();
    if (t < H2) {
        float v = partial[t] + partial[t + 128] + b2[j];
        out[(size_t)b * H2 + j] = fmaxf(v, 0.f);
    }
}

extern "C" void kernel_launch(void* const* d_in, const int* in_sizes, int n_in,
                              void* d_out, int out_size, void* d_ws, size_t ws_size,
                              hipStream_t stream) {
    const float* data = (const float*)d_in[0];
    const float* gw   = (const float*)d_in[1];
    const float* gb   = (const float*)d_in[2];
    const float* W1   = (const float*)d_in[3];
    const float* b1   = (const float*)d_in[4];
    const float* W2   = (const float*)d_in[5];
    const float* b2   = (const float*)d_in[6];
    const int*   ei   = (const int*)d_in[7];   // harness passes integers as int32
    float* out = (float*)d_out;

    const int B  = 256;
    const int H1 = in_sizes[4];          // 1024
    const int H2 = in_sizes[6];          // 128
    const int N  = in_sizes[3] / H1;     // 10000
    const int E  = in_sizes[7] / 2;      // 160000

    float* ws   = (float*)d_ws;
    float* deg  = ws;                        // N
    float* dinv = deg + N;                   // N
    float* xwT  = dinv + N;                  // N*B   (16B-aligned: 2N*4=80000 bytes)
    float* aggT = xwT + (size_t)N * B;       // N*B
    float* hraw = aggT + (size_t)N * B;      // B*H1  (contiguous after aggT)

    // zero deg (N floats) and aggT..hraw (N*B + B*H1 floats) via kernels —
    // guaranteed to be captured & replayed as graph nodes.
    {
        int n4 = N / 4;  // 2500
        zero4_kernel<<<(n4 + 255) / 256, 256, 0, stream>>>((float4*)deg, n4);
        int m4 = (N * B + B * H1) / 4;  // 705536
        zero4_kernel<<<(m4 + 255) / 256, 256, 0, stream>>>((float4*)aggT, m4);
    }

    deg_kernel<<<(E + 255) / 256, 256, 0, stream>>>(ei + E, deg, E);
    dinv_kernel<<<(N + 255) / 256, 256, 0, stream>>>(deg, dinv, N);

    dim3 tg((N + 31) / 32, B / 32);
    transpose_scale<<<tg, dim3(32, 8), 0, stream>>>(data, gw, xwT, N, B);

    scatter_kernel<<<(E + 3) / 4, 256, 0, stream>>>(ei, dinv, xwT, aggT, E, B);

    int SKZ = (N + 639) / 640;  // 16
    dim3 g1(H1 / 64, B / 64, SKZ);
    gemm1_kernel<<<g1, 256, 0, stream>>>(aggT, xwT, dinv, W1, gb, hraw, N, B, H1);

    bias_relu_kernel<<<(B * H1 + 255) / 256, 256, 0, stream>>>(hraw, b1, B * H1, H1);

    gemm2_kernel<<<B, 256, 0, stream>>>(hraw, W2, b2, out, H1, H2);
}

// Round 4
// 360.853 us; speedup vs baseline: 2.3456x; 2.3456x over previous
//
#include <hip/hip_runtime.h>
#include <hip/hip_bf16.h>

// Sizes (derived at launch, expected values):
// B=256, N=10000, E=160000, H1=1024, H2=128
// NOTE: harness passes integer inputs as int32 (edge_index -> const int*).
// NOTE: zeroing via kernels only (graph-replay-safe; round-2 lesson).
// Round 4: scatter(atomicAdd x41M, 536us) -> dst-CSR + gather (atomic-free).

__global__ void zero4_kernel(float4* __restrict__ p, int n4) {
    int i = blockIdx.x * blockDim.x + threadIdx.x;
    if (i < n4) p[i] = make_float4(0.f, 0.f, 0.f, 0.f);
}

__global__ void deg_kernel(const int* __restrict__ dst, int* __restrict__ deg, int E) {
    int i = blockIdx.x * blockDim.x + threadIdx.x;
    if (i < E) atomicAdd(&deg[dst[i]], 1);
}

// single-block exclusive scan over deg[N] -> rowptr[N+1]
__global__ void scan_kernel(const int* __restrict__ deg, int* __restrict__ rowptr, int N) {
    __shared__ int sums[1024];
    int t = threadIdx.x;
    int per = (N + 1023) / 1024;
    int base = t * per;
    int s = 0;
    for (int i = 0; i < per; ++i) {
        int idx = base + i;
        if (idx < N) s += deg[idx];
    }
    sums[t] = s;
    __syncthreads();
    for (int off = 1; off < 1024; off <<= 1) {
        int v = (t >= off) ? sums[t - off] : 0;
        __syncthreads();
        sums[t] += v;
        __syncthreads();
    }
    int run = (t == 0) ? 0 : sums[t - 1];
    for (int i = 0; i < per; ++i) {
        int idx = base + i;
        if (idx <= N) rowptr[idx] = run;
        if (idx < N) run += deg[idx];
    }
}

__global__ void dinv_kernel(const int* __restrict__ deg, float* __restrict__ dinv, int N) {
    int n = blockIdx.x * blockDim.x + threadIdx.x;
    if (n < N) dinv[n] = rsqrtf((float)deg[n] + 1.0f);  // +1 = self-loop
}

__global__ void fill_kernel(const int* __restrict__ ei, const float* __restrict__ dinv,
                            const int* __restrict__ rowptr, int* __restrict__ fill,
                            int* __restrict__ csr_src, float* __restrict__ csr_norm, int E) {
    int e = blockIdx.x * blockDim.x + threadIdx.x;
    if (e >= E) return;
    int s = ei[e], d = ei[E + e];
    int pos = rowptr[d] + atomicAdd(&fill[d], 1);
    csr_src[pos] = s;
    csr_norm[pos] = dinv[s] * dinv[d];
}

// data [B][N] -> xwT [N][B], scaled by gcn_w
__global__ void transpose_scale(const float* __restrict__ data, const float* __restrict__ gw,
                                float* __restrict__ xwT, int N, int B) {
    __shared__ float tile[32][33];
    float w = gw[0];
    int n0 = blockIdx.x * 32, b0 = blockIdx.y * 32;
#pragma unroll
    for (int i = 0; i < 4; ++i) {
        int b = b0 + threadIdx.y + i * 8;
        int n = n0 + threadIdx.x;
        float v = (n < N) ? data[(size_t)b * N + n] : 0.f;
        tile[threadIdx.y + i * 8][threadIdx.x] = v * w;
    }
    __syncthreads();
#pragma unroll
    for (int i = 0; i < 4; ++i) {
        int n = n0 + threadIdx.y + i * 8;
        int b = b0 + threadIdx.x;
        if (n < N) xwT[(size_t)n * B + b] = tile[threadIdx.x][threadIdx.y + i * 8];
    }
}

// one wave per dst row: aggT[row][:] = dinv[row]^2 * xwT[row][:] + sum_e norm_e * xwT[src_e][:]
__global__ void gather_kernel(const int* __restrict__ rowptr, const int* __restrict__ csr_src,
                              const float* __restrict__ csr_norm, const float* __restrict__ dinv,
                              const float* __restrict__ xwT, float* __restrict__ aggT,
                              int N, int B) {
    int row = blockIdx.x * 4 + (threadIdx.x >> 6);
    if (row >= N) return;
    int lane = threadIdx.x & 63;
    const int B4 = B >> 2;  // 64
    const float4* x4 = (const float4*)xwT;
    float di = dinv[row];
    float w = di * di;
    float4 v = x4[(size_t)row * B4 + lane];
    float4 acc;
    acc.x = v.x * w; acc.y = v.y * w; acc.z = v.z * w; acc.w = v.w * w;
    int i = rowptr[row], end = rowptr[row + 1];
    // unroll-by-2 to give the memory pipe two independent row-loads in flight
    for (; i + 1 < end; i += 2) {
        int s0 = csr_src[i], s1 = csr_src[i + 1];
        float n0 = csr_norm[i], n1 = csr_norm[i + 1];
        float4 u0 = x4[(size_t)s0 * B4 + lane];
        float4 u1 = x4[(size_t)s1 * B4 + lane];
        acc.x = fmaf(u0.x, n0, acc.x); acc.y = fmaf(u0.y, n0, acc.y);
        acc.z = fmaf(u0.z, n0, acc.z); acc.w = fmaf(u0.w, n0, acc.w);
        acc.x = fmaf(u1.x, n1, acc.x); acc.y = fmaf(u1.y, n1, acc.y);
        acc.z = fmaf(u1.z, n1, acc.z); acc.w = fmaf(u1.w, n1, acc.w);
    }
    if (i < end) {
        int s0 = csr_src[i];
        float n0 = csr_norm[i];
        float4 u0 = x4[(size_t)s0 * B4 + lane];
        acc.x = fmaf(u0.x, n0, acc.x); acc.y = fmaf(u0.y, n0, acc.y);
        acc.z = fmaf(u0.z, n0, acc.z); acc.w = fmaf(u0.w, n0, acc.w);
    }
    ((float4*)aggT)[(size_t)row * B4 + lane] = acc;
}

// split-K fp32 GEMM: h_raw[m][n] += sum_k g[m][k] * W1[k][n]
// g[m][k] = relu(aggT[k][m] + gcn_b)  (fused; aggT already includes self-loop)
__global__ void gemm1_kernel(const float* __restrict__ aggT, const float* __restrict__ W1,
                             const float* __restrict__ gcn_b, float* __restrict__ hraw,
                             int K, int B, int H1) {
    __shared__ float As[32][64];
    __shared__ float Bs[32][64];
    const int n0 = blockIdx.x * 64;
    const int m0 = blockIdx.y * 64;
    const int k0base = blockIdx.z * 640;
    const float gb = gcn_b[0];
    const int t = threadIdx.x;
    const int tx = t & 15, ty = t >> 4;
    float acc[4][4] = {};

    for (int ks = 0; ks < 20; ++ks) {
        int k0 = k0base + ks * 32;
#pragma unroll
        for (int i = 0; i < 8; ++i) {
            int idx = t + i * 256;
            int kk = idx >> 6, cc = idx & 63;
            int k = k0 + kk;
            float av = 0.f, bv = 0.f;
            if (k < K) {
                av = fmaxf(aggT[(size_t)k * B + (m0 + cc)] + gb, 0.f);
                bv = W1[(size_t)k * H1 + (n0 + cc)];
            }
            As[kk][cc] = av;
            Bs[kk][cc] = bv;
        }
        __syncthreads();
#pragma unroll 8
        for (int kk = 0; kk < 32; ++kk) {
            float a0 = As[kk][ty * 4 + 0], a1 = As[kk][ty * 4 + 1];
            float a2 = As[kk][ty * 4 + 2], a3 = As[kk][ty * 4 + 3];
            float b0 = Bs[kk][tx * 4 + 0], b1 = Bs[kk][tx * 4 + 1];
            float b2 = Bs[kk][tx * 4 + 2], b3 = Bs[kk][tx * 4 + 3];
            acc[0][0] = fmaf(a0, b0, acc[0][0]); acc[0][1] = fmaf(a0, b1, acc[0][1]);
            acc[0][2] = fmaf(a0, b2, acc[0][2]); acc[0][3] = fmaf(a0, b3, acc[0][3]);
            acc[1][0] = fmaf(a1, b0, acc[1][0]); acc[1][1] = fmaf(a1, b1, acc[1][1]);
            acc[1][2] = fmaf(a1, b2, acc[1][2]); acc[1][3] = fmaf(a1, b3, acc[1][3]);
            acc[2][0] = fmaf(a2, b0, acc[2][0]); acc[2][1] = fmaf(a2, b1, acc[2][1]);
            acc[2][2] = fmaf(a2, b2, acc[2][2]); acc[2][3] = fmaf(a2, b3, acc[2][3]);
            acc[3][0] = fmaf(a3, b0, acc[3][0]); acc[3][1] = fmaf(a3, b1, acc[3][1]);
            acc[3][2] = fmaf(a3, b2, acc[3][2]); acc[3][3] = fmaf(a3, b3, acc[3][3]);
        }
        __syncthreads();
    }
#pragma unroll
    for (int i = 0; i < 4; ++i) {
        int m = m0 + ty * 4 + i;
#pragma unroll
        for (int j = 0; j < 4; ++j) {
            atomicAdd(&hraw[(size_t)m * H1 + n0 + tx * 4 + j], acc[i][j]);
        }
    }
}

__global__ void bias_relu_kernel(float* __restrict__ h, const float* __restrict__ b1,
                                 int total, int H1) {
    int i = blockIdx.x * blockDim.x + threadIdx.x;
    if (i < total) h[i] = fmaxf(h[i] + b1[i & (H1 - 1)], 0.f);
}

// out[b][j] = relu(sum_k h[b][k]*W2[k][j] + b2[j]); block=256 (2 k-halves), grid=B
__global__ void gemm2_kernel(const float* __restrict__ h, const float* __restrict__ W2,
                             const float* __restrict__ b2, float* __restrict__ out,
                             int H1, int H2) {
    __shared__ float partial[256];
    int b = blockIdx.x;
    int t = threadIdx.x;
    int j = t & (H2 - 1);
    int half = t >> 7;
    const float* hrow = h + (size_t)b * H1;
    float sum = 0.f;
    int k0 = half * (H1 / 2), k1 = k0 + (H1 / 2);
    for (int k = k0; k < k1; ++k)
        sum = fmaf(hrow[k], W2[(size_t)k * H2 + j], sum);
    partial[t] = sum;
    __syncthreads();
    if (t < H2) {
        float v = partial[t] + partial[t + 128] + b2[j];
        out[(size_t)b * H2 + j] = fmaxf(v, 0.f);
    }
}

extern "C" void kernel_launch(void* const* d_in, const int* in_sizes, int n_in,
                              void* d_out, int out_size, void* d_ws, size_t ws_size,
                              hipStream_t stream) {
    const float* data = (const float*)d_in[0];
    const float* gw   = (const float*)d_in[1];
    const float* gb   = (const float*)d_in[2];
    const float* W1   = (const float*)d_in[3];
    const float* b1   = (const float*)d_in[4];
    const float* W2   = (const float*)d_in[5];
    const float* b2   = (const float*)d_in[6];
    const int*   ei   = (const int*)d_in[7];   // int32 per harness
    float* out = (float*)d_out;

    const int B  = 256;
    const int H1 = in_sizes[4];          // 1024
    const int H2 = in_sizes[6];          // 128
    const int N  = in_sizes[3] / H1;     // 10000
    const int E  = in_sizes[7] / 2;      // 160000

    // workspace layout (all 16B-aligned; N and E divisible by 4)
    float* ws      = (float*)d_ws;
    int*   deg     = (int*)ws;                       // N ints
    int*   fill    = deg + N;                        // N ints (contiguous w/ deg for one zero pass)
    int*   rowptr  = fill + N;                       // N+4 ints
    int*   csr_src = rowptr + N + 4;                 // E ints
    float* csr_nrm = (float*)(csr_src + E);          // E floats
    float* dinv    = csr_nrm + E;                    // N floats
    float* xwT     = dinv + N;                       // N*B floats
    float* aggT    = xwT + (size_t)N * B;            // N*B floats
    float* hraw    = aggT + (size_t)N * B;           // B*H1 floats

    // zero: deg+fill (2N ints) and hraw (B*H1 floats)
    zero4_kernel<<<(2 * N / 4 + 255) / 256, 256, 0, stream>>>((float4*)deg, 2 * N / 4);
    zero4_kernel<<<(B * H1 / 4 + 255) / 256, 256, 0, stream>>>((float4*)hraw, B * H1 / 4);

    deg_kernel<<<(E + 255) / 256, 256, 0, stream>>>(ei + E, deg, E);
    scan_kernel<<<1, 1024, 0, stream>>>(deg, rowptr, N);
    dinv_kernel<<<(N + 255) / 256, 256, 0, stream>>>(deg, dinv, N);
    fill_kernel<<<(E + 255) / 256, 256, 0, stream>>>(ei, dinv, rowptr, fill, csr_src, csr_nrm, E);

    dim3 tg((N + 31) / 32, B / 32);
    transpose_scale<<<tg, dim3(32, 8), 0, stream>>>(data, gw, xwT, N, B);

    gather_kernel<<<(N + 3) / 4, 256, 0, stream>>>(rowptr, csr_src, csr_nrm, dinv, xwT, aggT, N, B);

    int SKZ = (N + 639) / 640;  // 16
    dim3 g1(H1 / 64, B / 64, SKZ);
    gemm1_kernel<<<g1, 256, 0, stream>>>(aggT, W1, gb, hraw, N, B, H1);

    bias_relu_kernel<<<(B * H1 + 255) / 256, 256, 0, stream>>>(hraw, b1, B * H1, H1);

    gemm2_kernel<<<B, 256, 0, stream>>>(hraw, W2, b2, out, H1, H2);
}

// Round 5
// 205.955 us; speedup vs baseline: 4.1096x; 1.7521x over previous
//
#include <hip/hip_runtime.h>
#include <hip/hip_bf16.h>

// B=256, N=10000, E=160000, H1=1024, H2=128
// - int inputs are int32 (round-1 lesson); zeroing via kernels (round-2 lesson)
// - GCN agg via dst-CSR gather, atomic-free (round-4 win)
// - Round 5: gemm1 -> bf16 MFMA + split-K partials (no atomics);
//            gemm2 -> 8-way K-split + ILP + reduce (was 186us latency-bound)

typedef __attribute__((ext_vector_type(8))) short short8v;   // 8 bf16 = 4 VGPRs
typedef __attribute__((ext_vector_type(4))) float f32x4;

__device__ inline short f2bf(float f) {  // RNE fp32->bf16
    union { float f; unsigned u; } v; v.f = f;
    unsigned r = v.u + 0x7fffu + ((v.u >> 16) & 1u);
    return (short)(r >> 16);
}

__global__ void zero4_kernel(float4* __restrict__ p, int n4) {
    int i = blockIdx.x * blockDim.x + threadIdx.x;
    if (i < n4) p[i] = make_float4(0.f, 0.f, 0.f, 0.f);
}

__global__ void deg_kernel(const int* __restrict__ dst, int* __restrict__ deg, int E) {
    int i = blockIdx.x * blockDim.x + threadIdx.x;
    if (i < E) atomicAdd(&deg[dst[i]], 1);
}

// single-block exclusive scan over deg[N] -> rowptr[N+1]
__global__ void scan_kernel(const int* __restrict__ deg, int* __restrict__ rowptr, int N) {
    __shared__ int sums[1024];
    int t = threadIdx.x;
    int per = (N + 1023) / 1024;
    int base = t * per;
    int s = 0;
    for (int i = 0; i < per; ++i) {
        int idx = base + i;
        if (idx < N) s += deg[idx];
    }
    sums[t] = s;
    __syncthreads();
    for (int off = 1; off < 1024; off <<= 1) {
        int v = (t >= off) ? sums[t - off] : 0;
        __syncthreads();
        sums[t] += v;
        __syncthreads();
    }
    int run = (t == 0) ? 0 : sums[t - 1];
    for (int i = 0; i < per; ++i) {
        int idx = base + i;
        if (idx <= N) rowptr[idx] = run;
        if (idx < N) run += deg[idx];
    }
}

__global__ void dinv_kernel(const int* __restrict__ deg, float* __restrict__ dinv, int N) {
    int n = blockIdx.x * blockDim.x + threadIdx.x;
    if (n < N) dinv[n] = rsqrtf((float)deg[n] + 1.0f);  // +1 = self-loop
}

__global__ void fill_kernel(const int* __restrict__ ei, const float* __restrict__ dinv,
                            const int* __restrict__ rowptr, int* __restrict__ fill,
                            int* __restrict__ csr_src, float* __restrict__ csr_norm, int E) {
    int e = blockIdx.x * blockDim.x + threadIdx.x;
    if (e >= E) return;
    int s = ei[e], d = ei[E + e];
    int pos = rowptr[d] + atomicAdd(&fill[d], 1);
    csr_src[pos] = s;
    csr_norm[pos] = dinv[s] * dinv[d];
}

// data [B][N] -> xwT [N][B], scaled by gcn_w
__global__ void transpose_scale(const float* __restrict__ data, const float* __restrict__ gw,
                                float* __restrict__ xwT, int N, int B) {
    __shared__ float tile[32][33];
    float w = gw[0];
    int n0 = blockIdx.x * 32, b0 = blockIdx.y * 32;
#pragma unroll
    for (int i = 0; i < 4; ++i) {
        int b = b0 + threadIdx.y + i * 8;
        int n = n0 + threadIdx.x;
        float v = (n < N) ? data[(size_t)b * N + n] : 0.f;
        tile[threadIdx.y + i * 8][threadIdx.x] = v * w;
    }
    __syncthreads();
#pragma unroll
    for (int i = 0; i < 4; ++i) {
        int n = n0 + threadIdx.y + i * 8;
        int b = b0 + threadIdx.x;
        if (n < N) xwT[(size_t)n * B + b] = tile[threadIdx.x][threadIdx.y + i * 8];
    }
}

// one wave per dst row: aggT[row][:] = dinv[row]^2 * xwT[row][:] + sum_e norm_e * xwT[src_e][:]
__global__ void gather_kernel(const int* __restrict__ rowptr, const int* __restrict__ csr_src,
                              const float* __restrict__ csr_norm, const float* __restrict__ dinv,
                              const float* __restrict__ xwT, float* __restrict__ aggT,
                              int N, int B) {
    int row = blockIdx.x * 4 + (threadIdx.x >> 6);
    if (row >= N) return;
    int lane = threadIdx.x & 63;
    const int B4 = B >> 2;  // 64
    const float4* x4 = (const float4*)xwT;
    float di = dinv[row];
    float w = di * di;
    float4 v = x4[(size_t)row * B4 + lane];
    float4 acc;
    acc.x = v.x * w; acc.y = v.y * w; acc.z = v.z * w; acc.w = v.w * w;
    int i = rowptr[row], end = rowptr[row + 1];
    for (; i + 1 < end; i += 2) {
        int s0 = csr_src[i], s1 = csr_src[i + 1];
        float n0 = csr_norm[i], n1 = csr_norm[i + 1];
        float4 u0 = x4[(size_t)s0 * B4 + lane];
        float4 u1 = x4[(size_t)s1 * B4 + lane];
        acc.x = fmaf(u0.x, n0, acc.x); acc.y = fmaf(u0.y, n0, acc.y);
        acc.z = fmaf(u0.z, n0, acc.z); acc.w = fmaf(u0.w, n0, acc.w);
        acc.x = fmaf(u1.x, n1, acc.x); acc.y = fmaf(u1.y, n1, acc.y);
        acc.z = fmaf(u1.z, n1, acc.z); acc.w = fmaf(u1.w, n1, acc.w);
    }
    if (i < end) {
        int s0 = csr_src[i];
        float n0 = csr_norm[i];
        float4 u0 = x4[(size_t)s0 * B4 + lane];
        acc.x = fmaf(u0.x, n0, acc.x); acc.y = fmaf(u0.y, n0, acc.y);
        acc.z = fmaf(u0.z, n0, acc.z); acc.w = fmaf(u0.w, n0, acc.w);
    }
    ((float4*)aggT)[(size_t)row * B4 + lane] = acc;
}

// bf16 MFMA split-K GEMM1: hpart[z][m][n] = sum_{k in chunk} relu(aggT[k][m]+gb) * W1[k][n]
// tiles: 64m x 64n per block, 4 waves in 2x2 (each 32x32 = 2x2 MFMA 16x16x32)
// LDS: As[64 m][40 k-shorts], Bs[64 n][40] (stride 40 shorts = 80B, 16B-aligned rows)
#define KCHUNK 1280
#define KSTEPS 40
__global__ void gemm1_mfma(const float* __restrict__ aggT, const float* __restrict__ W1,
                           const float* __restrict__ gcn_b, float* __restrict__ hpart,
                           int K, int B, int H1) {
    __shared__ __align__(16) short As[64][40];
    __shared__ __align__(16) short Bs[64][40];
    const int n0 = blockIdx.x * 64;
    const int m0 = blockIdx.y * 64;
    const int kz = blockIdx.z * KCHUNK;
    const float gb = gcn_b[0];
    const int t = threadIdx.x;
    const int l = t & 63, w = t >> 6;
    const int wm = w >> 1, wn = w & 1;
    const int q = l >> 4, i16 = l & 15;
    const int sm = t & 63;          // staging column (m or n)
    const int sk4 = t >> 6;         // staging k-row group (0..3)

    f32x4 acc00 = {0.f, 0.f, 0.f, 0.f}, acc01 = acc00, acc10 = acc00, acc11 = acc00;

    for (int ks = 0; ks < KSTEPS; ++ks) {
        int k0 = kz + ks * 32;
#pragma unroll
        for (int p = 0; p < 8; ++p) {
            int kk = p * 4 + sk4;
            int k = k0 + kk;
            float av = 0.f, bv = 0.f;
            if (k < K) {
                av = fmaxf(aggT[(size_t)k * B + (m0 + sm)] + gb, 0.f);
                bv = W1[(size_t)k * H1 + (n0 + sm)];
            }
            As[sm][kk] = f2bf(av);
            Bs[sm][kk] = f2bf(bv);
        }
        __syncthreads();
        short8v a0 = *(const short8v*)&As[wm * 32 + i16][q * 8];
        short8v a1 = *(const short8v*)&As[wm * 32 + 16 + i16][q * 8];
        short8v b0 = *(const short8v*)&Bs[wn * 32 + i16][q * 8];
        short8v b1 = *(const short8v*)&Bs[wn * 32 + 16 + i16][q * 8];
        acc00 = __builtin_amdgcn_mfma_f32_16x16x32_bf16(a0, b0, acc00, 0, 0, 0);
        acc01 = __builtin_amdgcn_mfma_f32_16x16x32_bf16(a0, b1, acc01, 0, 0, 0);
        acc10 = __builtin_amdgcn_mfma_f32_16x16x32_bf16(a1, b0, acc10, 0, 0, 0);
        acc11 = __builtin_amdgcn_mfma_f32_16x16x32_bf16(a1, b1, acc11, 0, 0, 0);
        __syncthreads();
    }

    // C/D layout (HW-verified): col = lane&15, row = (lane>>4)*4 + reg
    float* hp = hpart + (size_t)blockIdx.z * 256 * 1024;
#pragma unroll
    for (int r = 0; r < 4; ++r) {
        int mr0 = m0 + wm * 32 + q * 4 + r;
        int nc0 = n0 + wn * 32 + i16;
        hp[(size_t)mr0 * 1024 + nc0]            = acc00[r];
        hp[(size_t)mr0 * 1024 + nc0 + 16]       = acc01[r];
        hp[(size_t)(mr0 + 16) * 1024 + nc0]      = acc10[r];
        hp[(size_t)(mr0 + 16) * 1024 + nc0 + 16] = acc11[r];
    }
}

// hraw[m][n] = relu(sum_z hpart[z][m][n] + b1[n])
__global__ void reduce1_kernel(const float* __restrict__ hpart, const float* __restrict__ b1,
                               float* __restrict__ hraw, int Z, int H1, int total) {
    int idx = blockIdx.x * blockDim.x + threadIdx.x;
    if (idx >= total) return;
    float s = 0.f;
    for (int z = 0; z < Z; ++z) s += hpart[(size_t)z * total + idx];
    hraw[idx] = fmaxf(s + b1[idx & (H1 - 1)], 0.f);
}

// gemm2 split-K: out2[ks][b][j] = sum_{k in chunk} h[b][k] * W2[k][j]
__global__ void gemm2_split(const float* __restrict__ h, const float* __restrict__ W2,
                            float* __restrict__ out2, int H1, int H2) {
    int ksid = blockIdx.x;               // 0..7
    int b = blockIdx.y;                  // 0..255
    int j = threadIdx.x;                 // 0..127
    const int KC = H1 / 8;               // 128
    const float* hrow = h + (size_t)b * H1 + ksid * KC;
    const float* w2p = W2 + (size_t)(ksid * KC) * H2 + j;
    float s0 = 0.f, s1 = 0.f, s2 = 0.f, s3 = 0.f;
#pragma unroll 8
    for (int k = 0; k < KC; k += 4) {
        s0 = fmaf(hrow[k],     w2p[(size_t)k * H2],       s0);
        s1 = fmaf(hrow[k + 1], w2p[(size_t)(k + 1) * H2], s1);
        s2 = fmaf(hrow[k + 2], w2p[(size_t)(k + 2) * H2], s2);
        s3 = fmaf(hrow[k + 3], w2p[(size_t)(k + 3) * H2], s3);
    }
    out2[((size_t)ksid * 256 + b) * H2 + j] = (s0 + s1) + (s2 + s3);
}

__global__ void reduce2_kernel(const float* __restrict__ out2, const float* __restrict__ b2,
                               float* __restrict__ out, int KS, int H2, int total) {
    int idx = blockIdx.x * blockDim.x + threadIdx.x;
    if (idx >= total) return;
    float s = 0.f;
    for (int z = 0; z < KS; ++z) s += out2[(size_t)z * total + idx];
    out[idx] = fmaxf(s + b2[idx & (H2 - 1)], 0.f);
}

extern "C" void kernel_launch(void* const* d_in, const int* in_sizes, int n_in,
                              void* d_out, int out_size, void* d_ws, size_t ws_size,
                              hipStream_t stream) {
    const float* data = (const float*)d_in[0];
    const float* gw   = (const float*)d_in[1];
    const float* gb   = (const float*)d_in[2];
    const float* W1   = (const float*)d_in[3];
    const float* b1   = (const float*)d_in[4];
    const float* W2   = (const float*)d_in[5];
    const float* b2   = (const float*)d_in[6];
    const int*   ei   = (const int*)d_in[7];
    float* out = (float*)d_out;

    const int B  = 256;
    const int H1 = in_sizes[4];          // 1024
    const int H2 = in_sizes[6];          // 128
    const int N  = in_sizes[3] / H1;     // 10000
    const int E  = in_sizes[7] / 2;      // 160000
    const int Z  = 8;                    // gemm1 split-K chunks (KCHUNK*Z >= N)
    const int KS = 8;                    // gemm2 split-K chunks

    float* ws      = (float*)d_ws;
    int*   deg     = (int*)ws;                       // N
    int*   fill    = deg + N;                        // N
    int*   rowptr  = fill + N;                       // N+4
    int*   csr_src = rowptr + N + 4;                 // E
    float* csr_nrm = (float*)(csr_src + E);          // E
    float* dinv    = csr_nrm + E;                    // N
    float* xwT     = dinv + N;                       // N*B  (recycled as hpart after gather)
    float* aggT    = xwT + (size_t)N * B;            // N*B
    float* hraw    = aggT + (size_t)N * B;           // B*H1
    float* out2    = hraw + (size_t)B * H1;          // KS*B*H2
    float* hpart   = xwT;                            // Z*B*H1 = 2.1M floats <= N*B = 2.56M

    zero4_kernel<<<(2 * N / 4 + 255) / 256, 256, 0, stream>>>((float4*)deg, 2 * N / 4);

    deg_kernel<<<(E + 255) / 256, 256, 0, stream>>>(ei + E, deg, E);
    scan_kernel<<<1, 1024, 0, stream>>>(deg, rowptr, N);
    dinv_kernel<<<(N + 255) / 256, 256, 0, stream>>>(deg, dinv, N);
    fill_kernel<<<(E + 255) / 256, 256, 0, stream>>>(ei, dinv, rowptr, fill, csr_src, csr_nrm, E);

    dim3 tg((N + 31) / 32, B / 32);
    transpose_scale<<<tg, dim3(32, 8), 0, stream>>>(data, gw, xwT, N, B);

    gather_kernel<<<(N + 3) / 4, 256, 0, stream>>>(rowptr, csr_src, csr_nrm, dinv, xwT, aggT, N, B);

    dim3 g1(H1 / 64, B / 64, Z);   // 16 x 4 x 8
    gemm1_mfma<<<g1, 256, 0, stream>>>(aggT, W1, gb, hpart, N, B, H1);

    reduce1_kernel<<<(B * H1 + 255) / 256, 256, 0, stream>>>(hpart, b1, hraw, Z, H1, B * H1);

    dim3 g2(KS, B);
    gemm2_split<<<g2, H2, 0, stream>>>(hraw, W2, out2, H1, H2);

    reduce2_kernel<<<(B * H2 + 255) / 256, 256, 0, stream>>>(out2, b2, out, KS, H2, B * H2);
}

// Round 6
// 133.535 us; speedup vs baseline: 6.3384x; 1.5423x over previous
//
#include <hip/hip_runtime.h>
#include <hip/hip_bf16.h>

// B=256, N=10000, E=160000, H1=1024, H2=128
// - int inputs are int32; zeroing via kernels (graph-replay-safe)
// - GCN agg via dst-CSR gather, atomic-free
// - Round 6: gemm1 operands pre-converted to bf16 in k-contiguous layouts,
//   staged via global_load_lds(16B, per-lane row addresses). Round-5 MFMA
//   staging (scalar loads + f2bf + conflicted LDS writes in-loop) was
//   9800 cyc/K-step with everything idle.

#define KPAD 10240

typedef __attribute__((ext_vector_type(8))) short short8v;   // 8 bf16
typedef __attribute__((ext_vector_type(4))) float f32x4;

__device__ inline short f2bf(float f) {  // RNE fp32->bf16
    union { float f; unsigned u; } v; v.f = f;
    unsigned r = v.u + 0x7fffu + ((v.u >> 16) & 1u);
    return (short)(r >> 16);
}

__device__ inline void gll16(const short* g, short* l) {
    __builtin_amdgcn_global_load_lds(
        (const __attribute__((address_space(1))) void*)g,
        (__attribute__((address_space(3))) void*)l, 16, 0, 0);
}

__global__ void zero4_kernel(float4* __restrict__ p, int n4) {
    int i = blockIdx.x * blockDim.x + threadIdx.x;
    if (i < n4) p[i] = make_float4(0.f, 0.f, 0.f, 0.f);
}

__global__ void deg_kernel(const int* __restrict__ dst, int* __restrict__ deg, int E) {
    int i = blockIdx.x * blockDim.x + threadIdx.x;
    if (i < E) atomicAdd(&deg[dst[i]], 1);
}

__global__ void scan_kernel(const int* __restrict__ deg, int* __restrict__ rowptr, int N) {
    __shared__ int sums[1024];
    int t = threadIdx.x;
    int per = (N + 1023) / 1024;
    int base = t * per;
    int s = 0;
    for (int i = 0; i < per; ++i) {
        int idx = base + i;
        if (idx < N) s += deg[idx];
    }
    sums[t] = s;
    __syncthreads();
    for (int off = 1; off < 1024; off <<= 1) {
        int v = (t >= off) ? sums[t - off] : 0;
        __syncthreads();
        sums[t] += v;
        __syncthreads();
    }
    int run = (t == 0) ? 0 : sums[t - 1];
    for (int i = 0; i < per; ++i) {
        int idx = base + i;
        if (idx <= N) rowptr[idx] = run;
        if (idx < N) run += deg[idx];
    }
}

__global__ void dinv_kernel(const int* __restrict__ deg, float* __restrict__ dinv, int N) {
    int n = blockIdx.x * blockDim.x + threadIdx.x;
    if (n < N) dinv[n] = rsqrtf((float)deg[n] + 1.0f);
}

__global__ void fill_kernel(const int* __restrict__ ei, const float* __restrict__ dinv,
                            const int* __restrict__ rowptr, int* __restrict__ fill,
                            int* __restrict__ csr_src, float* __restrict__ csr_norm, int E) {
    int e = blockIdx.x * blockDim.x + threadIdx.x;
    if (e >= E) return;
    int s = ei[e], d = ei[E + e];
    int pos = rowptr[d] + atomicAdd(&fill[d], 1);
    csr_src[pos] = s;
    csr_norm[pos] = dinv[s] * dinv[d];
}

// data [B][N] -> xwT [N][B] f32, scaled by gcn_w
__global__ void transpose_scale(const float* __restrict__ data, const float* __restrict__ gw,
                                float* __restrict__ xwT, int N, int B) {
    __shared__ float tile[32][33];
    float w = gw[0];
    int n0 = blockIdx.x * 32, b0 = blockIdx.y * 32;
#pragma unroll
    for (int i = 0; i < 4; ++i) {
        int b = b0 + threadIdx.y + i * 8;
        int n = n0 + threadIdx.x;
        float v = (n < N) ? data[(size_t)b * N + n] : 0.f;
        tile[threadIdx.y + i * 8][threadIdx.x] = v * w;
    }
    __syncthreads();
#pragma unroll
    for (int i = 0; i < 4; ++i) {
        int n = n0 + threadIdx.y + i * 8;
        int b = b0 + threadIdx.x;
        if (n < N) xwT[(size_t)n * B + b] = tile[threadIdx.x][threadIdx.y + i * 8];
    }
}

// one wave per dst row; writes A0[row][m] = bf16(relu(agg + gcn_b))
__global__ void gather_kernel(const int* __restrict__ rowptr, const int* __restrict__ csr_src,
                              const float* __restrict__ csr_norm, const float* __restrict__ dinv,
                              const float* __restrict__ gcn_b, const float* __restrict__ xwT,
                              short* __restrict__ A0, int N, int B) {
    int row = blockIdx.x * 4 + (threadIdx.x >> 6);
    if (row >= N) return;
    int lane = threadIdx.x & 63;
    const int B4 = B >> 2;
    const float4* x4 = (const float4*)xwT;
    float gb = gcn_b[0];
    float di = dinv[row];
    float w = di * di;
    float4 v = x4[(size_t)row * B4 + lane];
    float4 acc;
    acc.x = v.x * w; acc.y = v.y * w; acc.z = v.z * w; acc.w = v.w * w;
    int i = rowptr[row], end = rowptr[row + 1];
    for (; i + 1 < end; i += 2) {
        int s0 = csr_src[i], s1 = csr_src[i + 1];
        float n0 = csr_norm[i], n1 = csr_norm[i + 1];
        float4 u0 = x4[(size_t)s0 * B4 + lane];
        float4 u1 = x4[(size_t)s1 * B4 + lane];
        acc.x = fmaf(u0.x, n0, acc.x); acc.y = fmaf(u0.y, n0, acc.y);
        acc.z = fmaf(u0.z, n0, acc.z); acc.w = fmaf(u0.w, n0, acc.w);
        acc.x = fmaf(u1.x, n1, acc.x); acc.y = fmaf(u1.y, n1, acc.y);
        acc.z = fmaf(u1.z, n1, acc.z); acc.w = fmaf(u1.w, n1, acc.w);
    }
    if (i < end) {
        int s0 = csr_src[i];
        float n0 = csr_norm[i];
        float4 u0 = x4[(size_t)s0 * B4 + lane];
        acc.x = fmaf(u0.x, n0, acc.x); acc.y = fmaf(u0.y, n0, acc.y);
        acc.z = fmaf(u0.z, n0, acc.z); acc.w = fmaf(u0.w, n0, acc.w);
    }
    short4 s4;
    s4.x = f2bf(fmaxf(acc.x + gb, 0.f));
    s4.y = f2bf(fmaxf(acc.y + gb, 0.f));
    s4.z = f2bf(fmaxf(acc.z + gb, 0.f));
    s4.w = f2bf(fmaxf(acc.w + gb, 0.f));
    ((short4*)(A0 + (size_t)row * B))[lane] = s4;
}

// A0 [N][256] bf16 -> A [256][KPAD] bf16 (transpose, zero-pad k>=N)
__global__ void convertA(const short* __restrict__ A0, short* __restrict__ A, int K, int M) {
    __shared__ short tile[32][34];
    int k0 = blockIdx.x * 32, m0 = blockIdx.y * 32;
    int tx = threadIdx.x, ty = threadIdx.y;
#pragma unroll
    for (int i = 0; i < 4; ++i) {
        int k = k0 + ty + i * 8;
        short v = (k < K) ? A0[(size_t)k * M + m0 + tx] : (short)0;
        tile[tx][ty + i * 8] = v;
    }
    __syncthreads();
#pragma unroll
    for (int i = 0; i < 4; ++i) {
        int m = m0 + ty + i * 8;
        A[(size_t)m * KPAD + k0 + tx] = tile[ty + i * 8][tx];
    }
}

// W1 f32 [N][H1] -> W1T bf16 [H1][KPAD] (transpose+convert, zero-pad)
__global__ void convertB(const float* __restrict__ W1, short* __restrict__ W1T, int K, int H1) {
    __shared__ short tile[32][66];
    int k0 = blockIdx.x * 64;
    int h0 = blockIdx.y * 32;
    int t = threadIdx.x;
    int hl = t & 31, kr = t >> 5;   // read: 64 k-rows x 32 h
#pragma unroll
    for (int i = 0; i < 8; ++i) {
        int k = k0 + kr + i * 8;
        float v = (k < K) ? W1[(size_t)k * H1 + h0 + hl] : 0.f;
        tile[hl][kr + i * 8] = f2bf(v);
    }
    __syncthreads();
    int kl = t & 63, hr = t >> 6;   // write: 32 h-rows x 64 k
#pragma unroll
    for (int i = 0; i < 8; ++i) {
        int h = h0 + hr + i * 4;
        W1T[(size_t)h * KPAD + k0 + kl] = tile[hr + i * 4][kl];
    }
}

// bf16 MFMA split-K GEMM: hpart[z][m][n] = sum_k A[m][k] * W1T[n][k]
// 64x64 tile, 4 waves 2x2, K-chunk 1280 = 40 steps of 32.
// Staging: global_load_lds 16B, per-lane row addr (lane = tile row), LDS linear.
__global__ void gemm1_mfma(const short* __restrict__ A, const short* __restrict__ Wt,
                           float* __restrict__ hpart) {
    __shared__ __align__(16) short ldsA[2048];
    __shared__ __align__(16) short ldsB[2048];
    const int n0 = blockIdx.x * 64;
    const int m0 = blockIdx.y * 64;
    const int kz = blockIdx.z * 1280;
    const int t = threadIdx.x;
    const int l = t & 63, w = t >> 6;
    const int wm = w >> 1, wn = w & 1;
    const int q = l >> 4, i16 = l & 15;

    const short* gA = A + (size_t)(m0 + l) * KPAD + kz + w * 8;
    const short* gB = Wt + (size_t)(n0 + l) * KPAD + kz + w * 8;
    short* lA = &ldsA[w * 512];
    short* lB = &ldsB[w * 512];

    f32x4 acc00 = {0.f, 0.f, 0.f, 0.f}, acc01 = acc00, acc10 = acc00, acc11 = acc00;

    for (int ks = 0; ks < 40; ++ks) {
        gll16(gA, lA);          // wave w stages k-subchunk w of A tile
        gll16(gB, lB);          // and of B tile (lane = row, 16B of k)
        gA += 32; gB += 32;
        __syncthreads();        // drains vmcnt(0) -> LDS tile complete
        short8v a0 = *(const short8v*)&ldsA[q * 512 + (wm * 32 + i16) * 8];
        short8v a1 = *(const short8v*)&ldsA[q * 512 + (wm * 32 + 16 + i16) * 8];
        short8v b0 = *(const short8v*)&ldsB[q * 512 + (wn * 32 + i16) * 8];
        short8v b1 = *(const short8v*)&ldsB[q * 512 + (wn * 32 + 16 + i16) * 8];
        acc00 = __builtin_amdgcn_mfma_f32_16x16x32_bf16(a0, b0, acc00, 0, 0, 0);
        acc01 = __builtin_amdgcn_mfma_f32_16x16x32_bf16(a0, b1, acc01, 0, 0, 0);
        acc10 = __builtin_amdgcn_mfma_f32_16x16x32_bf16(a1, b0, acc10, 0, 0, 0);
        acc11 = __builtin_amdgcn_mfma_f32_16x16x32_bf16(a1, b1, acc11, 0, 0, 0);
        __syncthreads();
    }

    // C/D layout (HW-verified r5): col = lane&15, row = (lane>>4)*4 + reg
    float* hp = hpart + (size_t)blockIdx.z * (256 * 1024);
#pragma unroll
    for (int r = 0; r < 4; ++r) {
        int mr = m0 + wm * 32 + q * 4 + r;
        int nc = n0 + wn * 32 + i16;
        hp[(size_t)mr * 1024 + nc]             = acc00[r];
        hp[(size_t)mr * 1024 + nc + 16]        = acc01[r];
        hp[(size_t)(mr + 16) * 1024 + nc]      = acc10[r];
        hp[(size_t)(mr + 16) * 1024 + nc + 16] = acc11[r];
    }
}

__global__ void reduce1_kernel(const float* __restrict__ hpart, const float* __restrict__ b1,
                               float* __restrict__ hraw, int Z, int H1, int total) {
    int idx = blockIdx.x * blockDim.x + threadIdx.x;
    if (idx >= total) return;
    float s = 0.f;
    for (int z = 0; z < Z; ++z) s += hpart[(size_t)z * total + idx];
    hraw[idx] = fmaxf(s + b1[idx & (H1 - 1)], 0.f);
}

__global__ void gemm2_split(const float* __restrict__ h, const float* __restrict__ W2,
                            float* __restrict__ out2, int H1, int H2) {
    int ksid = blockIdx.x;
    int b = blockIdx.y;
    int j = threadIdx.x;
    const int KC = H1 / 8;
    const float* hrow = h + (size_t)b * H1 + ksid * KC;
    const float* w2p = W2 + (size_t)(ksid * KC) * H2 + j;
    float s0 = 0.f, s1 = 0.f, s2 = 0.f, s3 = 0.f;
#pragma unroll 8
    for (int k = 0; k < KC; k += 4) {
        s0 = fmaf(hrow[k],     w2p[(size_t)k * H2],       s0);
        s1 = fmaf(hrow[k + 1], w2p[(size_t)(k + 1) * H2], s1);
        s2 = fmaf(hrow[k + 2], w2p[(size_t)(k + 2) * H2], s2);
        s3 = fmaf(hrow[k + 3], w2p[(size_t)(k + 3) * H2], s3);
    }
    out2[((size_t)ksid * 256 + b) * H2 + j] = (s0 + s1) + (s2 + s3);
}

__global__ void reduce2_kernel(const float* __restrict__ out2, const float* __restrict__ b2,
                               float* __restrict__ out, int KS, int H2, int total) {
    int idx = blockIdx.x * blockDim.x + threadIdx.x;
    if (idx >= total) return;
    float s = 0.f;
    for (int z = 0; z < KS; ++z) s += out2[(size_t)z * total + idx];
    out[idx] = fmaxf(s + b2[idx & (H2 - 1)], 0.f);
}

extern "C" void kernel_launch(void* const* d_in, const int* in_sizes, int n_in,
                              void* d_out, int out_size, void* d_ws, size_t ws_size,
                              hipStream_t stream) {
    const float* data = (const float*)d_in[0];
    const float* gw   = (const float*)d_in[1];
    const float* gb   = (const float*)d_in[2];
    const float* W1   = (const float*)d_in[3];
    const float* b1   = (const float*)d_in[4];
    const float* W2   = (const float*)d_in[5];
    const float* b2   = (const float*)d_in[6];
    const int*   ei   = (const int*)d_in[7];
    float* out = (float*)d_out;

    const int B  = 256;
    const int H1 = in_sizes[4];          // 1024
    const int H2 = in_sizes[6];          // 128
    const int N  = in_sizes[3] / H1;     // 10000
    const int E  = in_sizes[7] / 2;      // 160000
    const int Z  = 8;                    // gemm1 split-K (Z*1280 = KPAD)
    const int KS = 8;                    // gemm2 split-K

    // ws layout (float offsets); W1T overlaps A0 (A0 dead after convertA);
    // hpart recycles xwT (dead after gather). Peak ~40 MB.
    float* ws      = (float*)d_ws;
    int*   deg     = (int*)ws;                               // 10000
    int*   fill    = deg + 10000;                            // 10000
    int*   rowptr  = fill + 10000;                           // 10016
    int*   csr_src = rowptr + 10016;                         // 160000
    float* csr_nrm = (float*)(csr_src + 160000);             // 160000
    float* dinv    = csr_nrm + 160000;                       // 10000
    float* xwT     = ws + 360016;                            // 2,560,000
    short* A       = (short*)(ws + 2920016);                 // 256*KPAD shorts
    short* A0      = (short*)(ws + 4230736);                 // N*256 shorts
    short* W1T     = (short*)(ws + 4230736);                 // H1*KPAD shorts (over A0)
    float* hraw    = ws + 9473616;                           // 262144
    float* out2    = ws + 9735760;                           // 262144
    float* hpart   = xwT;                                    // Z*B*H1 = 2,097,152

    zero4_kernel<<<(2 * N / 4 + 255) / 256, 256, 0, stream>>>((float4*)deg, 2 * N / 4);

    deg_kernel<<<(E + 255) / 256, 256, 0, stream>>>(ei + E, deg, E);
    scan_kernel<<<1, 1024, 0, stream>>>(deg, rowptr, N);
    dinv_kernel<<<(N + 255) / 256, 256, 0, stream>>>(deg, dinv, N);
    fill_kernel<<<(E + 255) / 256, 256, 0, stream>>>(ei, dinv, rowptr, fill, csr_src, csr_nrm, E);

    dim3 tg((N + 31) / 32, B / 32);
    transpose_scale<<<tg, dim3(32, 8), 0, stream>>>(data, gw, xwT, N, B);

    gather_kernel<<<(N + 3) / 4, 256, 0, stream>>>(rowptr, csr_src, csr_nrm, dinv, gb, xwT, A0, N, B);

    convertA<<<dim3(KPAD / 32, B / 32), dim3(32, 8), 0, stream>>>(A0, A, N, B);
    convertB<<<dim3(KPAD / 64, H1 / 32), 256, 0, stream>>>(W1, W1T, N, H1);   // after convertA (W1T over A0)

    dim3 g1(H1 / 64, B / 64, Z);   // 16 x 4 x 8 = 512 blocks
    gemm1_mfma<<<g1, 256, 0, stream>>>(A, W1T, hpart);

    reduce1_kernel<<<(B * H1 + 255) / 256, 256, 0, stream>>>(hpart, b1, hraw, Z, H1, B * H1);

    dim3 g2(KS, B);
    gemm2_split<<<g2, H2, 0, stream>>>(hraw, W2, out2, H1, H2);

    reduce2_kernel<<<(B * H2 + 255) / 256, 256, 0, stream>>>(out2, b2, out, KS, H2, B * H2);
}

// Round 7
// 124.191 us; speedup vs baseline: 6.8153x; 1.0752x over previous
//
#include <hip/hip_runtime.h>
#include <hip/hip_bf16.h>

// B=256, N=10000, E=160000, H1=1024, H2=128
// - int inputs are int32; zeroing via kernels (graph-replay-safe)
// - GCN agg via dst-CSR gather, atomic-free
// - bf16 MFMA gemm1 on pre-converted k-contiguous operands (round-6 win)
// - Round 7: bf16 xwT (halve gather traffic); gemm1 Z=16 + dbuf w/ counted
//   vmcnt + raw s_barrier; gemm2 fused (reduce1+split+reduce2 in one);
//   dinv merged into scan. 13 -> 10 launches.

#define KPAD 10240
#define NSTEPS 20   // K-steps per gemm1 block: KCHUNK=640 = 20*32
#define ZSPLIT 16

typedef __attribute__((ext_vector_type(8))) short short8v;   // 8 bf16
typedef __attribute__((ext_vector_type(4))) float f32x4;

__device__ inline short f2bf(float f) {  // RNE fp32->bf16
    union { float f; unsigned u; } v; v.f = f;
    unsigned r = v.u + 0x7fffu + ((v.u >> 16) & 1u);
    return (short)(r >> 16);
}

__device__ inline float bf2f(short s) {
    union { unsigned u; float f; } v;
    v.u = ((unsigned)(unsigned short)s) << 16;
    return v.f;
}

__device__ inline void gll16(const short* g, short* l) {
    __builtin_amdgcn_global_load_lds(
        (const __attribute__((address_space(1))) void*)g,
        (__attribute__((address_space(3))) void*)l, 16, 0, 0);
}

__global__ void zero4_kernel(float4* __restrict__ p, int n4) {
    int i = blockIdx.x * blockDim.x + threadIdx.x;
    if (i < n4) p[i] = make_float4(0.f, 0.f, 0.f, 0.f);
}

__global__ void deg_kernel(const int* __restrict__ dst, int* __restrict__ deg, int E) {
    int i = blockIdx.x * blockDim.x + threadIdx.x;
    if (i < E) atomicAdd(&deg[dst[i]], 1);
}

// single-block: exclusive scan deg->rowptr, plus dinv = rsqrt(deg+1)
__global__ void scan_kernel(const int* __restrict__ deg, int* __restrict__ rowptr,
                            float* __restrict__ dinv, int N) {
    __shared__ int sums[1024];
    int t = threadIdx.x;
    int per = (N + 1023) / 1024;
    int base = t * per;
    int s = 0;
    for (int i = 0; i < per; ++i) {
        int idx = base + i;
        if (idx < N) s += deg[idx];
    }
    sums[t] = s;
    __syncthreads();
    for (int off = 1; off < 1024; off <<= 1) {
        int v = (t >= off) ? sums[t - off] : 0;
        __syncthreads();
        sums[t] += v;
        __syncthreads();
    }
    int run = (t == 0) ? 0 : sums[t - 1];
    for (int i = 0; i < per; ++i) {
        int idx = base + i;
        if (idx <= N) rowptr[idx] = run;
        if (idx < N) {
            int d = deg[idx];
            run += d;
            dinv[idx] = rsqrtf((float)d + 1.0f);
        }
    }
}

__global__ void fill_kernel(const int* __restrict__ ei, const float* __restrict__ dinv,
                            const int* __restrict__ rowptr, int* __restrict__ fill,
                            int* __restrict__ csr_src, float* __restrict__ csr_norm, int E) {
    int e = blockIdx.x * blockDim.x + threadIdx.x;
    if (e >= E) return;
    int s = ei[e], d = ei[E + e];
    int pos = rowptr[d] + atomicAdd(&fill[d], 1);
    csr_src[pos] = s;
    csr_norm[pos] = dinv[s] * dinv[d];
}

// data [B][N] f32 -> xwT [N][B] bf16, scaled by gcn_w
__global__ void transpose_scale(const float* __restrict__ data, const float* __restrict__ gw,
                                short* __restrict__ xwT, int N, int B) {
    __shared__ short tile[32][34];
    float w = gw[0];
    int n0 = blockIdx.x * 32, b0 = blockIdx.y * 32;
    int tx = threadIdx.x, ty = threadIdx.y;
#pragma unroll
    for (int i = 0; i < 4; ++i) {
        int b = b0 + ty + i * 8;
        int n = n0 + tx;
        float v = (n < N) ? data[(size_t)b * N + n] : 0.f;
        tile[ty + i * 8][tx] = f2bf(v * w);   // tile[b_local][n_local]
    }
    __syncthreads();
#pragma unroll
    for (int i = 0; i < 4; ++i) {
        int n = n0 + ty + i * 8;
        if (n < N) xwT[(size_t)n * B + b0 + tx] = tile[tx][ty + i * 8];
    }
}

// one wave per dst row; A0[row][m] = bf16(relu(agg + gcn_b)); xwT is bf16
__global__ void gather_kernel(const int* __restrict__ rowptr, const int* __restrict__ csr_src,
                              const float* __restrict__ csr_norm, const float* __restrict__ dinv,
                              const float* __restrict__ gcn_b, const short* __restrict__ xwT,
                              short* __restrict__ A0, int N, int B) {
    int row = blockIdx.x * 4 + (threadIdx.x >> 6);
    if (row >= N) return;
    int lane = threadIdx.x & 63;
    const short4* x4 = (const short4*)xwT;
    const int B4 = B >> 2;   // 64 short4 per row
    float gb = gcn_b[0];
    float di = dinv[row];
    float w = di * di;
    short4 v = x4[(size_t)row * B4 + lane];
    float ax = bf2f(v.x) * w, ay = bf2f(v.y) * w, az = bf2f(v.z) * w, aw = bf2f(v.w) * w;
    int i = rowptr[row], end = rowptr[row + 1];
    for (; i + 1 < end; i += 2) {
        int s0 = csr_src[i], s1 = csr_src[i + 1];
        float n0 = csr_norm[i], n1 = csr_norm[i + 1];
        short4 u0 = x4[(size_t)s0 * B4 + lane];
        short4 u1 = x4[(size_t)s1 * B4 + lane];
        ax = fmaf(bf2f(u0.x), n0, ax); ay = fmaf(bf2f(u0.y), n0, ay);
        az = fmaf(bf2f(u0.z), n0, az); aw = fmaf(bf2f(u0.w), n0, aw);
        ax = fmaf(bf2f(u1.x), n1, ax); ay = fmaf(bf2f(u1.y), n1, ay);
        az = fmaf(bf2f(u1.z), n1, az); aw = fmaf(bf2f(u1.w), n1, aw);
    }
    if (i < end) {
        int s0 = csr_src[i];
        float n0 = csr_norm[i];
        short4 u0 = x4[(size_t)s0 * B4 + lane];
        ax = fmaf(bf2f(u0.x), n0, ax); ay = fmaf(bf2f(u0.y), n0, ay);
        az = fmaf(bf2f(u0.z), n0, az); aw = fmaf(bf2f(u0.w), n0, aw);
    }
    short4 s4;
    s4.x = f2bf(fmaxf(ax + gb, 0.f));
    s4.y = f2bf(fmaxf(ay + gb, 0.f));
    s4.z = f2bf(fmaxf(az + gb, 0.f));
    s4.w = f2bf(fmaxf(aw + gb, 0.f));
    ((short4*)(A0 + (size_t)row * B))[lane] = s4;
}

// A0 [N][256] bf16 -> A [256][KPAD] bf16 (transpose, zero-pad k>=N)
__global__ void convertA(const short* __restrict__ A0, short* __restrict__ A, int K, int M) {
    __shared__ short tile[32][34];
    int k0 = blockIdx.x * 32, m0 = blockIdx.y * 32;
    int tx = threadIdx.x, ty = threadIdx.y;
#pragma unroll
    for (int i = 0; i < 4; ++i) {
        int k = k0 + ty + i * 8;
        short v = (k < K) ? A0[(size_t)k * M + m0 + tx] : (short)0;
        tile[tx][ty + i * 8] = v;
    }
    __syncthreads();
#pragma unroll
    for (int i = 0; i < 4; ++i) {
        int m = m0 + ty + i * 8;
        A[(size_t)m * KPAD + k0 + tx] = tile[ty + i * 8][tx];
    }
}

// W1 f32 [N][H1] -> W1T bf16 [H1][KPAD] (transpose+convert, zero-pad)
__global__ void convertB(const float* __restrict__ W1, short* __restrict__ W1T, int K, int H1) {
    __shared__ short tile[32][66];
    int k0 = blockIdx.x * 64;
    int h0 = blockIdx.y * 32;
    int t = threadIdx.x;
    int hl = t & 31, kr = t >> 5;
#pragma unroll
    for (int i = 0; i < 8; ++i) {
        int k = k0 + kr + i * 8;
        float v = (k < K) ? W1[(size_t)k * H1 + h0 + hl] : 0.f;
        tile[hl][kr + i * 8] = f2bf(v);
    }
    __syncthreads();
    int kl = t & 63, hr = t >> 6;
#pragma unroll
    for (int i = 0; i < 8; ++i) {
        int h = h0 + hr + i * 4;
        W1T[(size_t)h * KPAD + k0 + kl] = tile[hr + i * 4][kl];
    }
}

// bf16 MFMA split-K GEMM: hpart[z][m][n] = sum_k A[m][k] * W1T[n][k]
// 64x64 tile, 4 waves 2x2; double-buffered LDS, counted vmcnt + raw barrier.
__global__ void gemm1_mfma(const short* __restrict__ A, const short* __restrict__ Wt,
                           float* __restrict__ hpart) {
    __shared__ __align__(16) short ldsA[2][2048];
    __shared__ __align__(16) short ldsB[2][2048];
    const int n0 = blockIdx.x * 64;
    const int m0 = blockIdx.y * 64;
    const int kz = blockIdx.z * (NSTEPS * 32);
    const int t = threadIdx.x;
    const int l = t & 63, w = t >> 6;
    const int wm = w >> 1, wn = w & 1;
    const int q = l >> 4, i16 = l & 15;

    const short* gA = A + (size_t)(m0 + l) * KPAD + kz + w * 8;
    const short* gB = Wt + (size_t)(n0 + l) * KPAD + kz + w * 8;

    f32x4 acc00 = {0.f, 0.f, 0.f, 0.f}, acc01 = acc00, acc10 = acc00, acc11 = acc00;

    // prologue: stage step 0 into buf 0
    gll16(gA, &ldsA[0][w * 512]);
    gll16(gB, &ldsB[0][w * 512]);
    gA += 32; gB += 32;

    for (int ks = 0; ks < NSTEPS; ++ks) {
        const int cur = ks & 1;
        if (ks + 1 < NSTEPS) {
            gll16(gA, &ldsA[cur ^ 1][w * 512]);   // prefetch next step
            gll16(gB, &ldsB[cur ^ 1][w * 512]);
            gA += 32; gB += 32;
            asm volatile("s_waitcnt vmcnt(2)" ::: "memory");  // current done, prefetch in flight
        } else {
            asm volatile("s_waitcnt vmcnt(0)" ::: "memory");
        }
        __builtin_amdgcn_s_barrier();
        __builtin_amdgcn_sched_barrier(0);
        const short* bA = &ldsA[cur][0];
        const short* bB = &ldsB[cur][0];
        short8v a0 = *(const short8v*)&bA[q * 512 + (wm * 32 + i16) * 8];
        short8v a1 = *(const short8v*)&bA[q * 512 + (wm * 32 + 16 + i16) * 8];
        short8v b0 = *(const short8v*)&bB[q * 512 + (wn * 32 + i16) * 8];
        short8v b1 = *(const short8v*)&bB[q * 512 + (wn * 32 + 16 + i16) * 8];
        acc00 = __builtin_amdgcn_mfma_f32_16x16x32_bf16(a0, b0, acc00, 0, 0, 0);
        acc01 = __builtin_amdgcn_mfma_f32_16x16x32_bf16(a0, b1, acc01, 0, 0, 0);
        acc10 = __builtin_amdgcn_mfma_f32_16x16x32_bf16(a1, b0, acc10, 0, 0, 0);
        acc11 = __builtin_amdgcn_mfma_f32_16x16x32_bf16(a1, b1, acc11, 0, 0, 0);
        __builtin_amdgcn_s_barrier();
    }

    // C/D layout (HW-verified): col = lane&15, row = (lane>>4)*4 + reg
    float* hp = hpart + (size_t)blockIdx.z * (256 * 1024);
#pragma unroll
    for (int r = 0; r < 4; ++r) {
        int mr = m0 + wm * 32 + q * 4 + r;
        int nc = n0 + wn * 32 + i16;
        hp[(size_t)mr * 1024 + nc]             = acc00[r];
        hp[(size_t)mr * 1024 + nc + 16]        = acc01[r];
        hp[(size_t)(mr + 16) * 1024 + nc]      = acc10[r];
        hp[(size_t)(mr + 16) * 1024 + nc + 16] = acc11[r];
    }
}

// fused: h[t] = relu(sum_z hpart[z][b][t] + b1[t]); out[b][j] = relu(h . W2[:,j] + b2[j])
// one block (1024 thr) per batch row b
__global__ void gemm2_fused(const float* __restrict__ hpart, const float* __restrict__ b1,
                            const float* __restrict__ W2, const float* __restrict__ b2,
                            float* __restrict__ out, int Z) {
    __shared__ float h_lds[1024];
    __shared__ float partial[8][128];
    int b = blockIdx.x, t = threadIdx.x;
    float s = 0.f;
    for (int z = 0; z < Z; ++z) s += hpart[(size_t)z * (256 * 1024) + b * 1024 + t];
    h_lds[t] = fmaxf(s + b1[t], 0.f);
    __syncthreads();
    int j = t & 127, oct = t >> 7;
    const float* w2p = W2 + (size_t)oct * 128 * 128 + j;
    const float* hp = h_lds + oct * 128;
    float s0 = 0.f, s1 = 0.f, s2 = 0.f, s3 = 0.f;
#pragma unroll 8
    for (int k = 0; k < 128; k += 4) {
        s0 = fmaf(hp[k],     w2p[(size_t)k * 128],       s0);
        s1 = fmaf(hp[k + 1], w2p[(size_t)(k + 1) * 128], s1);
        s2 = fmaf(hp[k + 2], w2p[(size_t)(k + 2) * 128], s2);
        s3 = fmaf(hp[k + 3], w2p[(size_t)(k + 3) * 128], s3);
    }
    partial[oct][j] = (s0 + s1) + (s2 + s3);
    __syncthreads();
    if (t < 128) {
        float v = b2[t];
#pragma unroll
        for (int o = 0; o < 8; ++o) v += partial[o][t];
        out[(size_t)b * 128 + t] = fmaxf(v, 0.f);
    }
}

extern "C" void kernel_launch(void* const* d_in, const int* in_sizes, int n_in,
                              void* d_out, int out_size, void* d_ws, size_t ws_size,
                              hipStream_t stream) {
    const float* data = (const float*)d_in[0];
    const float* gw   = (const float*)d_in[1];
    const float* gb   = (const float*)d_in[2];
    const float* W1   = (const float*)d_in[3];
    const float* b1   = (const float*)d_in[4];
    const float* W2   = (const float*)d_in[5];
    const float* b2   = (const float*)d_in[6];
    const int*   ei   = (const int*)d_in[7];
    float* out = (float*)d_out;

    const int B  = 256;
    const int H1 = in_sizes[4];          // 1024
    const int H2 = in_sizes[6];          // 128
    const int N  = in_sizes[3] / H1;     // 10000
    const int E  = in_sizes[7] / 2;      // 160000
    const int NP = 10240;                // padded N for layout

    // int region (offsets in 4B words)
    int* iws = (int*)d_ws;
    int*   deg     = iws;                            // NP
    int*   fill    = deg + NP;                       // NP
    int*   rowptr  = fill + NP;                      // NP
    int*   csr_src = rowptr + NP;                    // E
    float* csr_nrm = (float*)(csr_src + E);          // E
    float* dinv    = csr_nrm + E;                    // NP
    // short region
    short* S    = (short*)(dinv + NP);
    short* A    = S;                                 // 256*KPAD          = 2,621,440
    short* W1T  = A + (size_t)256 * KPAD;            // 1024*KPAD         = 10,485,760
    short* xwT  = W1T + (size_t)1024 * KPAD;         // N*B               = 2,560,000
    short* A0   = xwT + (size_t)N * B;               // N*B               = 2,560,000
    // hpart overlays xwT+A0 (both dead by gemm1) and extends past them
    float* hpart = (float*)xwT;                      // ZSPLIT*256*1024 f32 = 16.8 MB

    zero4_kernel<<<(2 * NP / 4 + 255) / 256, 256, 0, stream>>>((float4*)deg, 2 * NP / 4);

    deg_kernel<<<(E + 255) / 256, 256, 0, stream>>>(ei + E, deg, E);
    scan_kernel<<<1, 1024, 0, stream>>>(deg, rowptr, dinv, N);
    fill_kernel<<<(E + 255) / 256, 256, 0, stream>>>(ei, dinv, rowptr, fill, csr_src, csr_nrm, E);

    dim3 tg((N + 31) / 32, B / 32);
    transpose_scale<<<tg, dim3(32, 8), 0, stream>>>(data, gw, xwT, N, B);

    gather_kernel<<<(N + 3) / 4, 256, 0, stream>>>(rowptr, csr_src, csr_nrm, dinv, gb, xwT, A0, N, B);

    convertA<<<dim3(KPAD / 32, B / 32), dim3(32, 8), 0, stream>>>(A0, A, N, B);
    convertB<<<dim3(KPAD / 64, H1 / 32), 256, 0, stream>>>(W1, W1T, N, H1);

    dim3 g1(H1 / 64, B / 64, ZSPLIT);   // 16 x 4 x 16 = 1024 blocks
    gemm1_mfma<<<g1, 256, 0, stream>>>(A, W1T, hpart);

    gemm2_fused<<<B, 1024, 0, stream>>>(hpart, b1, W2, b2, out, ZSPLIT);
}

// Round 8
// 120.197 us; speedup vs baseline: 7.0418x; 1.0332x over previous
//
#include <hip/hip_runtime.h>
#include <hip/hip_bf16.h>

// B=256, N=10000, E=160000, H1=1024, H2=128
// - int inputs are int32; zeroing via kernels (graph-replay-safe)
// - GCN agg via dst-CSR gather, atomic-free; norm computed in gather (r8)
// - bf16 MFMA gemm1, pre-converted k-contiguous operands, global_load_lds(16B)
// - Round 8: gemm1 128x128 tile / 8 waves (halves L2 traffic, 2x MFMA per
//   barrier); fill no longer materializes csr_norm.

#define KPAD 10240
#define NSTEPS 20   // K-steps per gemm1 block: KCHUNK=640 = 20*32
#define ZSPLIT 16

typedef __attribute__((ext_vector_type(8))) short short8v;   // 8 bf16
typedef __attribute__((ext_vector_type(4))) float f32x4;

__device__ inline short f2bf(float f) {  // RNE fp32->bf16
    union { float f; unsigned u; } v; v.f = f;
    unsigned r = v.u + 0x7fffu + ((v.u >> 16) & 1u);
    return (short)(r >> 16);
}

__device__ inline float bf2f(short s) {
    union { unsigned u; float f; } v;
    v.u = ((unsigned)(unsigned short)s) << 16;
    return v.f;
}

__device__ inline void gll16(const short* g, short* l) {
    __builtin_amdgcn_global_load_lds(
        (const __attribute__((address_space(1))) void*)g,
        (__attribute__((address_space(3))) void*)l, 16, 0, 0);
}

__global__ void zero4_kernel(float4* __restrict__ p, int n4) {
    int i = blockIdx.x * blockDim.x + threadIdx.x;
    if (i < n4) p[i] = make_float4(0.f, 0.f, 0.f, 0.f);
}

__global__ void deg_kernel(const int* __restrict__ dst, int* __restrict__ deg, int E) {
    int i = blockIdx.x * blockDim.x + threadIdx.x;
    if (i < E) atomicAdd(&deg[dst[i]], 1);
}

// single-block: exclusive scan deg->rowptr, plus dinv = rsqrt(deg+1)
__global__ void scan_kernel(const int* __restrict__ deg, int* __restrict__ rowptr,
                            float* __restrict__ dinv, int N) {
    __shared__ int sums[1024];
    int t = threadIdx.x;
    int per = (N + 1023) / 1024;
    int base = t * per;
    int s = 0;
    for (int i = 0; i < per; ++i) {
        int idx = base + i;
        if (idx < N) s += deg[idx];
    }
    sums[t] = s;
    __syncthreads();
    for (int off = 1; off < 1024; off <<= 1) {
        int v = (t >= off) ? sums[t - off] : 0;
        __syncthreads();
        sums[t] += v;
        __syncthreads();
    }
    int run = (t == 0) ? 0 : sums[t - 1];
    for (int i = 0; i < per; ++i) {
        int idx = base + i;
        if (idx <= N) rowptr[idx] = run;
        if (idx < N) {
            int d = deg[idx];
            run += d;
            dinv[idx] = rsqrtf((float)d + 1.0f);
        }
    }
}

__global__ void fill_kernel(const int* __restrict__ ei, const int* __restrict__ rowptr,
                            int* __restrict__ fill, int* __restrict__ csr_src, int E) {
    int e = blockIdx.x * blockDim.x + threadIdx.x;
    if (e >= E) return;
    int s = ei[e], d = ei[E + e];
    int pos = rowptr[d] + atomicAdd(&fill[d], 1);
    csr_src[pos] = s;
}

// data [B][N] f32 -> xwT [N][B] bf16, scaled by gcn_w
__global__ void transpose_scale(const float* __restrict__ data, const float* __restrict__ gw,
                                short* __restrict__ xwT, int N, int B) {
    __shared__ short tile[32][34];
    float w = gw[0];
    int n0 = blockIdx.x * 32, b0 = blockIdx.y * 32;
    int tx = threadIdx.x, ty = threadIdx.y;
#pragma unroll
    for (int i = 0; i < 4; ++i) {
        int b = b0 + ty + i * 8;
        int n = n0 + tx;
        float v = (n < N) ? data[(size_t)b * N + n] : 0.f;
        tile[ty + i * 8][tx] = f2bf(v * w);   // tile[b_local][n_local]
    }
    __syncthreads();
#pragma unroll
    for (int i = 0; i < 4; ++i) {
        int n = n0 + ty + i * 8;
        if (n < N) xwT[(size_t)n * B + b0 + tx] = tile[tx][ty + i * 8];
    }
}

// one wave per dst row; A0[row][m] = bf16(relu(agg + gcn_b)); xwT is bf16
// norm computed inline: dinv[src]*dinv[row] (dinv is 40KB, cache-resident)
__global__ void gather_kernel(const int* __restrict__ rowptr, const int* __restrict__ csr_src,
                              const float* __restrict__ dinv, const float* __restrict__ gcn_b,
                              const short* __restrict__ xwT, short* __restrict__ A0,
                              int N, int B) {
    int row = blockIdx.x * 4 + (threadIdx.x >> 6);
    if (row >= N) return;
    int lane = threadIdx.x & 63;
    const short4* x4 = (const short4*)xwT;
    const int B4 = B >> 2;   // 64 short4 per row
    float gb = gcn_b[0];
    float di = dinv[row];
    float w = di * di;
    short4 v = x4[(size_t)row * B4 + lane];
    float ax = bf2f(v.x) * w, ay = bf2f(v.y) * w, az = bf2f(v.z) * w, aw = bf2f(v.w) * w;
    int i = rowptr[row], end = rowptr[row + 1];
    for (; i + 1 < end; i += 2) {
        int s0 = csr_src[i], s1 = csr_src[i + 1];
        float n0 = dinv[s0] * di, n1 = dinv[s1] * di;
        short4 u0 = x4[(size_t)s0 * B4 + lane];
        short4 u1 = x4[(size_t)s1 * B4 + lane];
        ax = fmaf(bf2f(u0.x), n0, ax); ay = fmaf(bf2f(u0.y), n0, ay);
        az = fmaf(bf2f(u0.z), n0, az); aw = fmaf(bf2f(u0.w), n0, aw);
        ax = fmaf(bf2f(u1.x), n1, ax); ay = fmaf(bf2f(u1.y), n1, ay);
        az = fmaf(bf2f(u1.z), n1, az); aw = fmaf(bf2f(u1.w), n1, aw);
    }
    if (i < end) {
        int s0 = csr_src[i];
        float n0 = dinv[s0] * di;
        short4 u0 = x4[(size_t)s0 * B4 + lane];
        ax = fmaf(bf2f(u0.x), n0, ax); ay = fmaf(bf2f(u0.y), n0, ay);
        az = fmaf(bf2f(u0.z), n0, az); aw = fmaf(bf2f(u0.w), n0, aw);
    }
    short4 s4;
    s4.x = f2bf(fmaxf(ax + gb, 0.f));
    s4.y = f2bf(fmaxf(ay + gb, 0.f));
    s4.z = f2bf(fmaxf(az + gb, 0.f));
    s4.w = f2bf(fmaxf(aw + gb, 0.f));
    ((short4*)(A0 + (size_t)row * B))[lane] = s4;
}

// A0 [N][256] bf16 -> A [256][KPAD] bf16 (transpose, zero-pad k>=N)
__global__ void convertA(const short* __restrict__ A0, short* __restrict__ A, int K, int M) {
    __shared__ short tile[32][34];
    int k0 = blockIdx.x * 32, m0 = blockIdx.y * 32;
    int tx = threadIdx.x, ty = threadIdx.y;
#pragma unroll
    for (int i = 0; i < 4; ++i) {
        int k = k0 + ty + i * 8;
        short v = (k < K) ? A0[(size_t)k * M + m0 + tx] : (short)0;
        tile[tx][ty + i * 8] = v;
    }
    __syncthreads();
#pragma unroll
    for (int i = 0; i < 4; ++i) {
        int m = m0 + ty + i * 8;
        A[(size_t)m * KPAD + k0 + tx] = tile[ty + i * 8][tx];
    }
}

// W1 f32 [N][H1] -> W1T bf16 [H1][KPAD] (transpose+convert, zero-pad)
__global__ void convertB(const float* __restrict__ W1, short* __restrict__ W1T, int K, int H1) {
    __shared__ short tile[32][66];
    int k0 = blockIdx.x * 64;
    int h0 = blockIdx.y * 32;
    int t = threadIdx.x;
    int hl = t & 31, kr = t >> 5;
#pragma unroll
    for (int i = 0; i < 8; ++i) {
        int k = k0 + kr + i * 8;
        float v = (k < K) ? W1[(size_t)k * H1 + h0 + hl] : 0.f;
        tile[hl][kr + i * 8] = f2bf(v);
    }
    __syncthreads();
    int kl = t & 63, hr = t >> 6;
#pragma unroll
    for (int i = 0; i < 8; ++i) {
        int h = h0 + hr + i * 4;
        W1T[(size_t)h * KPAD + k0 + kl] = tile[hr + i * 4][kl];
    }
}

// bf16 MFMA split-K GEMM: hpart[z][m][n] = sum_k A[m][k] * W1T[n][k]
// 128x128 tile, 8 waves (2m x 4n), each wave 64m x 32n = 8 MFMA/K-step.
// LDS per buf: [kq 0..3][row 0..127][8 shorts] = 8KB each for A,B; dbuf.
// Staging: thread i stages row i&127, k-subchunk i>>7 (LDS byte = i*16,
// = wave-uniform base + lane*16 as global_load_lds requires).
__global__ void __launch_bounds__(512)
gemm1_mfma(const short* __restrict__ A, const short* __restrict__ Wt,
           float* __restrict__ hpart) {
    __shared__ __align__(16) short ldsA[2][4096];
    __shared__ __align__(16) short ldsB[2][4096];
    const int n0 = blockIdx.x * 128;
    const int m0 = blockIdx.y * 128;
    const int kz = blockIdx.z * (NSTEPS * 32);
    const int t = threadIdx.x;            // 0..511
    const int l = t & 63, w = t >> 6;     // lane, wave 0..7
    const int wm = w >> 2, wn = w & 3;    // 2m x 4n wave grid
    const int q = l >> 4, i16 = l & 15;

    const int sRow = t & 127, sKq = t >> 7;
    const short* gA = A + (size_t)(m0 + sRow) * KPAD + kz + sKq * 8;
    const short* gB = Wt + (size_t)(n0 + sRow) * KPAD + kz + sKq * 8;
    const int ldst = w * 512;             // shorts: wave-uniform base (byte = w*1024)

    f32x4 acc[4][2];
#pragma unroll
    for (int mi = 0; mi < 4; ++mi)
#pragma unroll
        for (int ni = 0; ni < 2; ++ni) acc[mi][ni] = (f32x4){0.f, 0.f, 0.f, 0.f};

    // prologue: stage step 0 into buf 0
    gll16(gA, &ldsA[0][ldst]);
    gll16(gB, &ldsB[0][ldst]);
    gA += 32; gB += 32;

    for (int ks = 0; ks < NSTEPS; ++ks) {
        const int cur = ks & 1;
        if (ks + 1 < NSTEPS) {
            gll16(gA, &ldsA[cur ^ 1][ldst]);   // prefetch next step
            gll16(gB, &ldsB[cur ^ 1][ldst]);
            gA += 32; gB += 32;
            asm volatile("s_waitcnt vmcnt(2)" ::: "memory");  // cur done, prefetch in flight
        } else {
            asm volatile("s_waitcnt vmcnt(0)" ::: "memory");
        }
        __builtin_amdgcn_s_barrier();
        __builtin_amdgcn_sched_barrier(0);
        const short* bA = &ldsA[cur][0];
        const short* bB = &ldsB[cur][0];
        short8v a[4], b[2];
#pragma unroll
        for (int mi = 0; mi < 4; ++mi)
            a[mi] = *(const short8v*)&bA[q * 1024 + (wm * 64 + mi * 16 + i16) * 8];
#pragma unroll
        for (int ni = 0; ni < 2; ++ni)
            b[ni] = *(const short8v*)&bB[q * 1024 + (wn * 32 + ni * 16 + i16) * 8];
#pragma unroll
        for (int mi = 0; mi < 4; ++mi)
#pragma unroll
            for (int ni = 0; ni < 2; ++ni)
                acc[mi][ni] = __builtin_amdgcn_mfma_f32_16x16x32_bf16(a[mi], b[ni], acc[mi][ni], 0, 0, 0);
        __builtin_amdgcn_s_barrier();
    }

    // C/D layout (HW-verified): col = lane&15, row = (lane>>4)*4 + reg
    float* hp = hpart + (size_t)blockIdx.z * (256 * 1024);
#pragma unroll
    for (int mi = 0; mi < 4; ++mi) {
#pragma unroll
        for (int ni = 0; ni < 2; ++ni) {
#pragma unroll
            for (int r = 0; r < 4; ++r) {
                int mr = m0 + wm * 64 + mi * 16 + q * 4 + r;
                int nc = n0 + wn * 32 + ni * 16 + i16;
                hp[(size_t)mr * 1024 + nc] = acc[mi][ni][r];
            }
        }
    }
}

// fused: h[t] = relu(sum_z hpart[z][b][t] + b1[t]); out[b][j] = relu(h . W2[:,j] + b2[j])
__global__ void gemm2_fused(const float* __restrict__ hpart, const float* __restrict__ b1,
                            const float* __restrict__ W2, const float* __restrict__ b2,
                            float* __restrict__ out, int Z) {
    __shared__ float h_lds[1024];
    __shared__ float partial[8][128];
    int b = blockIdx.x, t = threadIdx.x;
    float s = 0.f;
    for (int z = 0; z < Z; ++z) s += hpart[(size_t)z * (256 * 1024) + b * 1024 + t];
    h_lds[t] = fmaxf(s + b1[t], 0.f);
    __syncthreads();
    int j = t & 127, oct = t >> 7;
    const float* w2p = W2 + (size_t)oct * 128 * 128 + j;
    const float* hp = h_lds + oct * 128;
    float s0 = 0.f, s1 = 0.f, s2 = 0.f, s3 = 0.f;
#pragma unroll 8
    for (int k = 0; k < 128; k += 4) {
        s0 = fmaf(hp[k],     w2p[(size_t)k * 128],       s0);
        s1 = fmaf(hp[k + 1], w2p[(size_t)(k + 1) * 128], s1);
        s2 = fmaf(hp[k + 2], w2p[(size_t)(k + 2) * 128], s2);
        s3 = fmaf(hp[k + 3], w2p[(size_t)(k + 3) * 128], s3);
    }
    partial[oct][j] = (s0 + s1) + (s2 + s3);
    __syncthreads();
    if (t < 128) {
        float v = b2[t];
#pragma unroll
        for (int o = 0; o < 8; ++o) v += partial[o][t];
        out[(size_t)b * 128 + t] = fmaxf(v, 0.f);
    }
}

extern "C" void kernel_launch(void* const* d_in, const int* in_sizes, int n_in,
                              void* d_out, int out_size, void* d_ws, size_t ws_size,
                              hipStream_t stream) {
    const float* data = (const float*)d_in[0];
    const float* gw   = (const float*)d_in[1];
    const float* gb   = (const float*)d_in[2];
    const float* W1   = (const float*)d_in[3];
    const float* b1   = (const float*)d_in[4];
    const float* W2   = (const float*)d_in[5];
    const float* b2   = (const float*)d_in[6];
    const int*   ei   = (const int*)d_in[7];
    float* out = (float*)d_out;

    const int B  = 256;
    const int H1 = in_sizes[4];          // 1024
    const int H2 = in_sizes[6];          // 128
    const int N  = in_sizes[3] / H1;     // 10000
    const int E  = in_sizes[7] / 2;      // 160000
    const int NP = 10240;

    int* iws = (int*)d_ws;
    int*   deg     = iws;                            // NP
    int*   fill    = deg + NP;                       // NP
    int*   rowptr  = fill + NP;                      // NP
    int*   csr_src = rowptr + NP;                    // E
    float* dinv    = (float*)(csr_src + E);          // NP
    short* S    = (short*)(dinv + NP);
    short* A    = S;                                 // 256*KPAD
    short* W1T  = A + (size_t)256 * KPAD;            // 1024*KPAD
    short* xwT  = W1T + (size_t)1024 * KPAD;         // N*B
    short* A0   = xwT + (size_t)N * B;               // N*B
    float* hpart = (float*)xwT;                      // ZSPLIT*256*1024 f32 (overlays xwT/A0 + beyond)

    zero4_kernel<<<(2 * NP / 4 + 255) / 256, 256, 0, stream>>>((float4*)deg, 2 * NP / 4);

    deg_kernel<<<(E + 255) / 256, 256, 0, stream>>>(ei + E, deg, E);
    scan_kernel<<<1, 1024, 0, stream>>>(deg, rowptr, dinv, N);
    fill_kernel<<<(E + 255) / 256, 256, 0, stream>>>(ei, rowptr, fill, csr_src, E);

    dim3 tg((N + 31) / 32, B / 32);
    transpose_scale<<<tg, dim3(32, 8), 0, stream>>>(data, gw, xwT, N, B);

    gather_kernel<<<(N + 3) / 4, 256, 0, stream>>>(rowptr, csr_src, dinv, gb, xwT, A0, N, B);

    convertA<<<dim3(KPAD / 32, B / 32), dim3(32, 8), 0, stream>>>(A0, A, N, B);
    convertB<<<dim3(KPAD / 64, H1 / 32), 256, 0, stream>>>(W1, W1T, N, H1);

    dim3 g1(H1 / 128, B / 128, ZSPLIT);   // 8 x 2 x 16 = 256 blocks
    gemm1_mfma<<<g1, 512, 0, stream>>>(A, W1T, hpart);

    gemm2_fused<<<B, 1024, 0, stream>>>(hpart, b1, W2, b2, out, ZSPLIT);
}

// Round 9
// 90.645 us; speedup vs baseline: 9.3375x; 1.3260x over previous
//
#include <hip/hip_runtime.h>
#include <hip/hip_bf16.h>

// B=256, N=10000, E=160000, H1=1024, H2=128
// - int inputs are int32; zeroing via kernels (graph-replay-safe)
// - GCN agg via dst-ELL gather (width 64, avg deg 16; P(overflow)~1e-55),
//   atomic-free aggregation, dinv computed inline from cnt
// - bf16 MFMA gemm1 (128x128 tile, 8 waves, global_load_lds dbuf, vmcnt(2))
// - Round 9: 10 -> 6 launches: pack = transpose+convertB+zero(cnt);
//   ELL kills the single-block scan; dinv folded into gather.

#define KPAD 10240
#define NSTEPS 20   // K-steps per gemm1 block: KCHUNK=640 = 20*32
#define ZSPLIT 16
#define ELLW 64

typedef __attribute__((ext_vector_type(8))) short short8v;   // 8 bf16
typedef __attribute__((ext_vector_type(4))) float f32x4;

__device__ inline short f2bf(float f) {  // RNE fp32->bf16
    union { float f; unsigned u; } v; v.f = f;
    unsigned r = v.u + 0x7fffu + ((v.u >> 16) & 1u);
    return (short)(r >> 16);
}

__device__ inline float bf2f(short s) {
    union { unsigned u; float f; } v;
    v.u = ((unsigned)(unsigned short)s) << 16;
    return v.f;
}

__device__ inline void gll16(const short* g, short* l) {
    __builtin_amdgcn_global_load_lds(
        (const __attribute__((address_space(1))) void*)g,
        (__attribute__((address_space(3))) void*)l, 16, 0, 0);
}

// fused: transpose_scale (data->xwT bf16) | convertB (W1->W1T bf16) | zero cnt
__global__ void pack_kernel(const float* __restrict__ data, const float* __restrict__ gw,
                            short* __restrict__ xwT, const float* __restrict__ W1,
                            short* __restrict__ W1T, float4* __restrict__ cntz,
                            int N, int B, int H1, int tTiles, int cTiles) {
    __shared__ short tile[32][66];
    int id = blockIdx.x, t = threadIdx.x;
    if (id < tTiles) {
        // data [B][N] f32 -> xwT [N][B] bf16, scaled by gcn_w
        int nt = (N + 31) >> 5;
        int xb = id % nt, yb = id / nt;
        int n0 = xb * 32, b0 = yb * 32;
        float w = gw[0];
        int tx = t & 31, ty = t >> 5;
#pragma unroll
        for (int i = 0; i < 4; ++i) {
            int b = b0 + ty + i * 8;
            int n = n0 + tx;
            float v = (n < N) ? data[(size_t)b * N + n] : 0.f;
            tile[ty + i * 8][tx] = f2bf(v * w);
        }
        __syncthreads();
#pragma unroll
        for (int i = 0; i < 4; ++i) {
            int n = n0 + ty + i * 8;
            if (n < N) xwT[(size_t)n * B + b0 + tx] = tile[tx][ty + i * 8];
        }
    } else if (id < tTiles + cTiles) {
        // W1 f32 [N][H1] -> W1T bf16 [H1][KPAD], zero-padded k>=N
        int c = id - tTiles;
        int nk = KPAD >> 6;
        int kx = c % nk, hy = c / nk;
        int k0 = kx * 64, h0 = hy * 32;
        int hl = t & 31, kr = t >> 5;
#pragma unroll
        for (int i = 0; i < 8; ++i) {
            int k = k0 + kr + i * 8;
            float v = (k < N) ? W1[(size_t)k * H1 + h0 + hl] : 0.f;
            tile[hl][kr + i * 8] = f2bf(v);
        }
        __syncthreads();
        int kl = t & 63, hr = t >> 6;
#pragma unroll
        for (int i = 0; i < 8; ++i) {
            int h = h0 + hr + i * 4;
            W1T[(size_t)h * KPAD + k0 + kl] = tile[hr + i * 4][kl];
        }
    } else {
        // zero cnt (NP ints = NP/4 float4)
        int i = (id - tTiles - cTiles) * 256 + t;
        cntz[i] = make_float4(0.f, 0.f, 0.f, 0.f);
    }
}

__global__ void ell_fill(const int* __restrict__ ei, int* __restrict__ cnt,
                         int* __restrict__ ell, int E) {
    int e = blockIdx.x * blockDim.x + threadIdx.x;
    if (e >= E) return;
    int s = ei[e], d = ei[E + e];
    int c = atomicAdd(&cnt[d], 1);
    if (c < ELLW) ell[(d << 6) + c] = s;   // clamp is defensive; never hit
}

// one wave per dst row; A0[row][m] = bf16(relu(agg + gcn_b))
// dinv computed inline from cnt (40KB, cache-resident)
__global__ void gather_kernel(const int* __restrict__ cnt, const int* __restrict__ ell,
                              const float* __restrict__ gcn_b, const short* __restrict__ xwT,
                              short* __restrict__ A0, int N, int B) {
    int row = blockIdx.x * 4 + (threadIdx.x >> 6);
    if (row >= N) return;
    int lane = threadIdx.x & 63;
    const short4* x4 = (const short4*)xwT;
    const int B4 = B >> 2;   // 64 short4 per row
    float gb = gcn_b[0];
    int dcnt = cnt[row];
    float di = rsqrtf((float)dcnt + 1.0f);
    float w = di * di;
    short4 v = x4[(size_t)row * B4 + lane];
    float ax = bf2f(v.x) * w, ay = bf2f(v.y) * w, az = bf2f(v.z) * w, aw = bf2f(v.w) * w;
    const int* er = ell + ((size_t)row << 6);
    int m = dcnt < ELLW ? dcnt : ELLW;
    int i = 0;
    for (; i + 1 < m; i += 2) {
        int s0 = er[i], s1 = er[i + 1];
        float n0 = rsqrtf((float)cnt[s0] + 1.0f) * di;
        float n1 = rsqrtf((float)cnt[s1] + 1.0f) * di;
        short4 u0 = x4[(size_t)s0 * B4 + lane];
        short4 u1 = x4[(size_t)s1 * B4 + lane];
        ax = fmaf(bf2f(u0.x), n0, ax); ay = fmaf(bf2f(u0.y), n0, ay);
        az = fmaf(bf2f(u0.z), n0, az); aw = fmaf(bf2f(u0.w), n0, aw);
        ax = fmaf(bf2f(u1.x), n1, ax); ay = fmaf(bf2f(u1.y), n1, ay);
        az = fmaf(bf2f(u1.z), n1, az); aw = fmaf(bf2f(u1.w), n1, aw);
    }
    if (i < m) {
        int s0 = er[i];
        float n0 = rsqrtf((float)cnt[s0] + 1.0f) * di;
        short4 u0 = x4[(size_t)s0 * B4 + lane];
        ax = fmaf(bf2f(u0.x), n0, ax); ay = fmaf(bf2f(u0.y), n0, ay);
        az = fmaf(bf2f(u0.z), n0, az); aw = fmaf(bf2f(u0.w), n0, aw);
    }
    short4 s4;
    s4.x = f2bf(fmaxf(ax + gb, 0.f));
    s4.y = f2bf(fmaxf(ay + gb, 0.f));
    s4.z = f2bf(fmaxf(az + gb, 0.f));
    s4.w = f2bf(fmaxf(aw + gb, 0.f));
    ((short4*)(A0 + (size_t)row * B))[lane] = s4;
}

// A0 [N][256] bf16 -> A [256][KPAD] bf16 (transpose, zero-pad k>=N)
__global__ void convertA(const short* __restrict__ A0, short* __restrict__ A, int K, int M) {
    __shared__ short tile[32][34];
    int k0 = blockIdx.x * 32, m0 = blockIdx.y * 32;
    int tx = threadIdx.x, ty = threadIdx.y;
#pragma unroll
    for (int i = 0; i < 4; ++i) {
        int k = k0 + ty + i * 8;
        short v = (k < K) ? A0[(size_t)k * M + m0 + tx] : (short)0;
        tile[tx][ty + i * 8] = v;
    }
    __syncthreads();
#pragma unroll
    for (int i = 0; i < 4; ++i) {
        int m = m0 + ty + i * 8;
        A[(size_t)m * KPAD + k0 + tx] = tile[ty + i * 8][tx];
    }
}

// bf16 MFMA split-K GEMM: hpart[z][m][n] = sum_k A[m][k] * W1T[n][k]
// 128x128 tile, 8 waves (2m x 4n), 8 MFMA/K-step/wave; dbuf + vmcnt(2).
__global__ void __launch_bounds__(512)
gemm1_mfma(const short* __restrict__ A, const short* __restrict__ Wt,
           float* __restrict__ hpart) {
    __shared__ __align__(16) short ldsA[2][4096];
    __shared__ __align__(16) short ldsB[2][4096];
    const int n0 = blockIdx.x * 128;
    const int m0 = blockIdx.y * 128;
    const int kz = blockIdx.z * (NSTEPS * 32);
    const int t = threadIdx.x;            // 0..511
    const int l = t & 63, w = t >> 6;     // lane, wave 0..7
    const int wm = w >> 2, wn = w & 3;    // 2m x 4n wave grid
    const int q = l >> 4, i16 = l & 15;

    const int sRow = t & 127, sKq = t >> 7;
    const short* gA = A + (size_t)(m0 + sRow) * KPAD + kz + sKq * 8;
    const short* gB = Wt + (size_t)(n0 + sRow) * KPAD + kz + sKq * 8;
    const int ldst = w * 512;             // shorts: wave-uniform base

    f32x4 acc[4][2];
#pragma unroll
    for (int mi = 0; mi < 4; ++mi)
#pragma unroll
        for (int ni = 0; ni < 2; ++ni) acc[mi][ni] = (f32x4){0.f, 0.f, 0.f, 0.f};

    gll16(gA, &ldsA[0][ldst]);
    gll16(gB, &ldsB[0][ldst]);
    gA += 32; gB += 32;

    for (int ks = 0; ks < NSTEPS; ++ks) {
        const int cur = ks & 1;
        if (ks + 1 < NSTEPS) {
            gll16(gA, &ldsA[cur ^ 1][ldst]);
            gll16(gB, &ldsB[cur ^ 1][ldst]);
            gA += 32; gB += 32;
            asm volatile("s_waitcnt vmcnt(2)" ::: "memory");
        } else {
            asm volatile("s_waitcnt vmcnt(0)" ::: "memory");
        }
        __builtin_amdgcn_s_barrier();
        __builtin_amdgcn_sched_barrier(0);
        const short* bA = &ldsA[cur][0];
        const short* bB = &ldsB[cur][0];
        short8v a[4], b[2];
#pragma unroll
        for (int mi = 0; mi < 4; ++mi)
            a[mi] = *(const short8v*)&bA[q * 1024 + (wm * 64 + mi * 16 + i16) * 8];
#pragma unroll
        for (int ni = 0; ni < 2; ++ni)
            b[ni] = *(const short8v*)&bB[q * 1024 + (wn * 32 + ni * 16 + i16) * 8];
#pragma unroll
        for (int mi = 0; mi < 4; ++mi)
#pragma unroll
            for (int ni = 0; ni < 2; ++ni)
                acc[mi][ni] = __builtin_amdgcn_mfma_f32_16x16x32_bf16(a[mi], b[ni], acc[mi][ni], 0, 0, 0);
        __builtin_amdgcn_s_barrier();
    }

    // C/D layout (HW-verified): col = lane&15, row = (lane>>4)*4 + reg
    float* hp = hpart + (size_t)blockIdx.z * (256 * 1024);
#pragma unroll
    for (int mi = 0; mi < 4; ++mi) {
#pragma unroll
        for (int ni = 0; ni < 2; ++ni) {
#pragma unroll
            for (int r = 0; r < 4; ++r) {
                int mr = m0 + wm * 64 + mi * 16 + q * 4 + r;
                int nc = n0 + wn * 32 + ni * 16 + i16;
                hp[(size_t)mr * 1024 + nc] = acc[mi][ni][r];
            }
        }
    }
}

// fused: h[t] = relu(sum_z hpart[z][b][t] + b1[t]); out[b][j] = relu(h . W2[:,j] + b2[j])
__global__ void gemm2_fused(const float* __restrict__ hpart, const float* __restrict__ b1,
                            const float* __restrict__ W2, const float* __restrict__ b2,
                            float* __restrict__ out, int Z) {
    __shared__ float h_lds[1024];
    __shared__ float partial[8][128];
    int b = blockIdx.x, t = threadIdx.x;
    float s = 0.f;
    for (int z = 0; z < Z; ++z) s += hpart[(size_t)z * (256 * 1024) + b * 1024 + t];
    h_lds[t] = fmaxf(s + b1[t], 0.f);
    __syncthreads();
    int j = t & 127, oct = t >> 7;
    const float* w2p = W2 + (size_t)oct * 128 * 128 + j;
    const float* hp = h_lds + oct * 128;
    float s0 = 0.f, s1 = 0.f, s2 = 0.f, s3 = 0.f;
#pragma unroll 8
    for (int k = 0; k < 128; k += 4) {
        s0 = fmaf(hp[k],     w2p[(size_t)k * 128],       s0);
        s1 = fmaf(hp[k + 1], w2p[(size_t)(k + 1) * 128], s1);
        s2 = fmaf(hp[k + 2], w2p[(size_t)(k + 2) * 128], s2);
        s3 = fmaf(hp[k + 3], w2p[(size_t)(k + 3) * 128], s3);
    }
    partial[oct][j] = (s0 + s1) + (s2 + s3);
    __syncthreads();
    if (t < 128) {
        float v = b2[t];
#pragma unroll
        for (int o = 0; o < 8; ++o) v += partial[o][t];
        out[(size_t)b * 128 + t] = fmaxf(v, 0.f);
    }
}

extern "C" void kernel_launch(void* const* d_in, const int* in_sizes, int n_in,
                              void* d_out, int out_size, void* d_ws, size_t ws_size,
                              hipStream_t stream) {
    const float* data = (const float*)d_in[0];
    const float* gw   = (const float*)d_in[1];
    const float* gb   = (const float*)d_in[2];
    const float* W1   = (const float*)d_in[3];
    const float* b1   = (const float*)d_in[4];
    const float* W2   = (const float*)d_in[5];
    const float* b2   = (const float*)d_in[6];
    const int*   ei   = (const int*)d_in[7];
    float* out = (float*)d_out;

    const int B  = 256;
    const int H1 = in_sizes[4];          // 1024
    const int H2 = in_sizes[6];          // 128
    const int N  = in_sizes[3] / H1;     // 10000
    const int E  = in_sizes[7] / 2;      // 160000
    const int NP = 10240;

    int* iws = (int*)d_ws;
    int*   cnt  = iws;                               // NP ints
    int*   ell  = cnt + NP;                          // NP*ELLW ints
    short* S    = (short*)(ell + (size_t)NP * ELLW);
    short* A    = S;                                 // 256*KPAD
    short* W1T  = A + (size_t)256 * KPAD;            // 1024*KPAD
    short* xwT  = W1T + (size_t)1024 * KPAD;         // N*B
    short* A0   = xwT + (size_t)N * B;               // N*B
    float* hpart = (float*)xwT;                      // ZSPLIT*256*1024 f32 (overlays xwT/A0+)

    const int tTiles = ((N + 31) / 32) * (B / 32);       // 2504
    const int cTiles = (KPAD / 64) * (H1 / 32);          // 5120
    const int zBlks  = NP / 1024;                        // 10 (NP/4 float4 / 256 thr)

    pack_kernel<<<tTiles + cTiles + zBlks, 256, 0, stream>>>(
        data, gw, xwT, W1, W1T, (float4*)cnt, N, B, H1, tTiles, cTiles);

    ell_fill<<<(E + 255) / 256, 256, 0, stream>>>(ei, cnt, ell, E);

    gather_kernel<<<(N + 3) / 4, 256, 0, stream>>>(cnt, ell, gb, xwT, A0, N, B);

    convertA<<<dim3(KPAD / 32, B / 32), dim3(32, 8), 0, stream>>>(A0, A, N, B);

    dim3 g1(H1 / 128, B / 128, ZSPLIT);   // 8 x 2 x 16 = 256 blocks
    gemm1_mfma<<<g1, 512, 0, stream>>>(A, W1T, hpart);

    gemm2_fused<<<B, 1024, 0, stream>>>(hpart, b1, W2, b2, out, ZSPLIT);
}